// Round 7
// baseline (1203.313 us; speedup 1.0000x reference)
//
#include <hip/hip_runtime.h>
#include <hip/hip_bf16.h>

// Problem constants
#define B_  64
#define T_  256
#define D_  384
#define H_  6
#define HD_ 64
#define L_  6
#define V_  65
#define BT  (B_*T_)     // 16384 tokens

typedef __hip_bfloat16 bf16;
typedef unsigned short u16;
typedef short s16;
typedef __attribute__((ext_vector_type(8))) short bf16x8;   // 8 bf16 = 4 VGPR
typedef __attribute__((ext_vector_type(4))) float f32x4;

// Per-layer weight buffer element offsets (bf16 elems)
#define OFF_QKV   0            // rows n = mat*384+h*64+hd, [n][k] 1152x384
#define OFF_PROJ  442368       // [n][k] 384x384
#define OFF_W1T   589824       // [n][k] 1536x384
#define OFF_W2T   1179648      // [n][k] 384x1536
#define OFF_BPROJ 1769472
#define OFF_B1    1769856
#define OFF_B2    1771392
#define OFF_LN1G  1771776
#define OFF_LN1B  1772160
#define OFF_LN2G  1772544
#define OFF_LN2B  1772928
#define WBUF_E    1773312
// Head buffer
#define HOFF_WHT  0            // [n][k] 65x384
#define HOFF_BH   24960
#define HOFF_LNFG 25088
#define HOFF_LNFB 25472
#define HBUF_E    25856

__device__ __forceinline__ float u2f(u16 u) {
  union { unsigned i; float f; } c; c.i = ((unsigned)u) << 16; return c.f;
}
__device__ __forceinline__ bf16 f2b(float x) { return __float2bfloat16(x); }
__device__ __forceinline__ float b2f(bf16 x) { return __bfloat162float(x); }
__device__ __forceinline__ u16 f2u(float x) { bf16 h = f2b(x); return *(u16*)&h; }

__device__ __forceinline__ float pload(const void* p, size_t i, bool f32w) {
  return f32w ? ((const float*)p)[i] : u2f(((const u16*)p)[i]);
}

// XCD-aware swizzle: all n-tiles of one m-tile get block ids congruent mod 8
// -> same XCD -> A-row re-reads hit that XCD's L2. [guide §1: locality only]
__device__ __forceinline__ void swz(int gid, int ntc, int mtiles,
                                    int& nt, int& mblk) {
  if ((mtiles & 7) == 0) {
    int per = ntc << 3;            // 8 m-tiles per group
    int g   = gid / per;
    int rem = gid - g * per;
    nt   = rem >> 3;
    mblk = (g << 3) + (rem & 7);
  } else {
    nt   = gid / mtiles;
    mblk = gid - nt * mtiles;
  }
}

// ---------------------------------------------------------------------------
// Parallel per-tensor dtype detect (R8-proven).
// ---------------------------------------------------------------------------
__global__ __launch_bounds__(256) void detect_kernel(
    const void* p1,  const void* p2,  const void* p3,  const void* p4,
    const void* p5,  const void* p6,  const void* p7,  const void* p8,
    const void* p9,  const void* p10, const void* p11, const void* p12,
    const void* p13, const void* p14, const void* p15, const void* p16,
    const void* p17, const void* p18, const void* p19,
    const int* __restrict__ idx, unsigned* flags)
{
  const void* ps[20] = {nullptr, p1, p2, p3, p4, p5, p6, p7, p8, p9, p10,
                        p11, p12, p13, p14, p15, p16, p17, p18, p19};
  const int esz[20] = {16384, 24960, 98304, 884736, 884736, 884736, 884736,
                       2304, 3538944, 9216, 3538944, 2304, 2304, 2304, 2304,
                       2304, 384, 384, 24960, 65};
  __shared__ int r1[256], r2[256];
  int bid = blockIdx.x, tid = threadIdx.x;
  if (bid == 19) {
    int z = 0;
    for (int m = tid; m < 4096; m += 256) z += (idx[2 * m + 1] == 0) ? 1 : 0;
    r1[tid] = z; __syncthreads();
    for (int s = 128; s > 0; s >>= 1) {
      if (tid < s) r1[tid] += r1[tid + s];
      __syncthreads();
    }
    if (tid == 0) flags[20] = (r1[0] >= 4000) ? 1u : 0u;
    return;
  }
  int j = bid + 1;
  const u16* p = (const u16*)ps[j];
  int ns = esz[j] / 2; if (ns > 1024) ns = 1024;
  int band = 0, nz = 0;
  for (int i = tid; i < ns; i += 256) {
    u16 lo = p[2 * i], hi = p[2 * i + 1];
    int e = (lo >> 7) & 0xFF;
    band += (e >= 100 && e <= 127) ? 1 : 0;
    nz   += (lo | hi) ? 1 : 0;
  }
  r1[tid] = band; r2[tid] = nz; __syncthreads();
  for (int s = 128; s > 0; s >>= 1) {
    if (tid < s) { r1[tid] += r1[tid + s]; r2[tid] += r2[tid + s]; }
    __syncthreads();
  }
  if (tid == 0) flags[j] = (r2[0] > 0 && r1[0] * 2 < ns) ? 1u : 0u;
}

__global__ void const_kernel(float* out, int n, float val) {
  int i = blockIdx.x * 256 + threadIdx.x;
  if (i < n) out[i] = val;
}

// ---------------------------------------------------------------------------
// Weight convert+transpose to bf16 (shared element map).
// ---------------------------------------------------------------------------
__device__ __forceinline__ float conv_val(int e, int l,
    const void* Wq, const void* Wk, const void* Wv, const void* Wproj,
    const void* bproj, const void* W1, const void* b1, const void* W2,
    const void* b2, const void* ln1g, const void* ln1b, const void* ln2g,
    const void* ln2b, const unsigned* __restrict__ flags)
{
  float v;
  if (e < OFF_PROJ) {                       // QKV^T per head
    int math = e / 24576;
    int rem  = e - math * 24576;
    int hd = rem / 384, d = rem - hd * 384;
    int mat = math / 6, hh = math - mat * 6;
    const void* src = (mat == 0 ? Wq : mat == 1 ? Wk : Wv);
    v = pload(src, ((size_t)(l * 6 + hh) * 384 + d) * 64 + hd, flags[3 + mat] != 0);
  } else if (e < OFF_W1T) {                 // Wproj^T
    int e2 = e - OFF_PROJ;
    int n = e2 / 384, d = e2 - n * 384;
    v = pload(Wproj, ((size_t)l * 384 + d) * 384 + n, flags[6] != 0);
  } else if (e < OFF_W2T) {                 // W1^T
    int e2 = e - OFF_W1T;
    int n = e2 / 384, d = e2 - n * 384;
    v = pload(W1, ((size_t)l * 384 + d) * 1536 + n, flags[8] != 0);
  } else if (e < OFF_BPROJ) {               // W2^T
    int e2 = e - OFF_W2T;
    int n = e2 / 1536, k = e2 - n * 1536;
    v = pload(W2, ((size_t)l * 1536 + k) * 384 + n, flags[10] != 0);
  } else {
    int e2 = e - OFF_BPROJ;
    if      (e2 < 384)  v = pload(bproj, (size_t)l * 384 + e2, flags[7] != 0);
    else if (e2 < 1920) v = pload(b1, (size_t)l * 1536 + (e2 - 384), flags[9] != 0);
    else if (e2 < 2304) v = pload(b2, (size_t)l * 384 + (e2 - 1920), flags[11] != 0);
    else if (e2 < 2688) v = pload(ln1g, (size_t)l * 384 + (e2 - 2304), flags[12] != 0);
    else if (e2 < 3072) v = pload(ln1b, (size_t)l * 384 + (e2 - 2688), flags[13] != 0);
    else if (e2 < 3456) v = pload(ln2g, (size_t)l * 384 + (e2 - 3072), flags[14] != 0);
    else                v = pload(ln2b, (size_t)l * 384 + (e2 - 3456), flags[15] != 0);
  }
  return v;
}

__global__ __launch_bounds__(256) void conv_layer(
    const void* Wq, const void* Wk, const void* Wv, const void* Wproj,
    const void* bproj, const void* W1, const void* b1, const void* W2,
    const void* b2, const void* ln1g, const void* ln1b, const void* ln2g,
    const void* ln2b, const unsigned* __restrict__ flags,
    bf16* __restrict__ dst, int l)
{
  int e = blockIdx.x * 256 + threadIdx.x;
  if (e >= WBUF_E) return;
  dst[e] = f2b(conv_val(e, l, Wq, Wk, Wv, Wproj, bproj, W1, b1, W2, b2,
                        ln1g, ln1b, ln2g, ln2b, flags));
}

// All 6 layers in one dispatch (R5: removes 5 launch gaps from the loop).
__global__ __launch_bounds__(256) void conv_all(
    const void* Wq, const void* Wk, const void* Wv, const void* Wproj,
    const void* bproj, const void* W1, const void* b1, const void* W2,
    const void* b2, const void* ln1g, const void* ln1b, const void* ln2g,
    const void* ln2b, const unsigned* __restrict__ flags,
    bf16* __restrict__ dst)
{
  int g = blockIdx.x * 256 + threadIdx.x;
  if (g >= 6 * WBUF_E) return;
  int l = g / WBUF_E;
  int e = g - l * WBUF_E;
  dst[g] = f2b(conv_val(e, l, Wq, Wk, Wv, Wproj, bproj, W1, b1, W2, b2,
                        ln1g, ln1b, ln2g, ln2b, flags));
}

__global__ __launch_bounds__(256) void conv_head(
    const void* Wh, const void* bh, const void* lnfg, const void* lnfb,
    const unsigned* __restrict__ flags, bf16* __restrict__ dst)
{
  int e = blockIdx.x * 256 + threadIdx.x;
  if (e >= HBUF_E) return;
  float v = 0.f;
  if (e < HOFF_BH) {                        // Whead^T [65][384]
    int n = e / 384, d = e - n * 384;
    v = pload(Wh, (size_t)d * 65 + n, flags[18] != 0);
  } else if (e < 25025) {
    v = pload(bh, e - HOFF_BH, flags[19] != 0);
  } else if (e < HOFF_LNFG) {
    v = 0.f;
  } else if (e < HOFF_LNFB) {
    v = pload(lnfg, e - HOFF_LNFG, flags[16] != 0);
  } else {
    v = pload(lnfb, e - HOFF_LNFB, flags[17] != 0);
  }
  dst[e] = f2b(v);
}

// ---------------------------------------------------------------------------
__global__ __launch_bounds__(256) void embed_kernel(
    const void* __restrict__ idx, const void* __restrict__ tok,
    const void* __restrict__ pos, bf16* __restrict__ x,
    const unsigned* __restrict__ flags)
{
  int i   = blockIdx.x * 256 + threadIdx.x;   // < BT*D_
  int tkn = i / D_;
  int d   = i - tkn * D_;
  int t   = tkn & (T_ - 1);
  long long tix;
  if (flags[20]) tix = ((const long long*)idx)[tkn];
  else           tix = ((const int*)idx)[tkn];
  float v = pload(tok, (size_t)tix * D_ + d, flags[1] != 0)
          + pload(pos, (size_t)t * D_ + d, flags[2] != 0);
  x[i] = f2b(v);
}

// ---------------------------------------------------------------------------
// LayerNorm: one wave per token -> hc (chunk-local). R16-proven.
// ---------------------------------------------------------------------------
__global__ __launch_bounds__(256) void lnw_kernel(
    const bf16* __restrict__ x, const u16* __restrict__ g,
    const u16* __restrict__ b, bf16* __restrict__ hc, int tok0)
{
  int w = threadIdx.x >> 6, lane = threadIdx.x & 63;
  int lm = blockIdx.x * 4 + w;
  const bf16* xr = x + (size_t)(tok0 + lm) * D_;
  float v[6]; float s = 0.f;
#pragma unroll
  for (int j = 0; j < 6; j++) { v[j] = b2f(xr[lane + 64 * j]); s += v[j]; }
#pragma unroll
  for (int o = 1; o < 64; o <<= 1) s += __shfl_xor(s, o, 64);
  float mean = s * (1.0f / D_);
  float sq = 0.f;
#pragma unroll
  for (int j = 0; j < 6; j++) { float d0 = v[j] - mean; sq += d0 * d0; }
#pragma unroll
  for (int o = 1; o < 64; o <<= 1) sq += __shfl_xor(sq, o, 64);
  float inv = 1.0f / sqrtf(sq * (1.0f / D_) + 1e-3f);
  bf16* hr = hc + (size_t)lm * D_;
#pragma unroll
  for (int j = 0; j < 6; j++) {
    int d = lane + 64 * j;
    hr[d] = f2b((v[j] - mean) * inv * u2f(g[d]) + u2f(b[d]));
  }
}

// ---------------------------------------------------------------------------
// mcore: m97-style MFMA GEMM core (R3-proven, single-buffer 2-barrier).
// Tile 128m x 128n x 64k, 256 threads. global_load_lds(16B) DMA staging into
// LINEAR LDS [rows][64] with content-XOR swizzle: LDS[row][slot] holds
// G[row][slot ^ (row&7)] (slot = 16B chunk index 0..7). Source pre-swizzle +
// read-side XOR are the same involution (rule 21); ds_read_b128 frags land
// 2-way = free. 32 KB LDS keeps ~5 blocks/CU (R4 lesson: 64 KB dbuf -> 2
// blocks/CU, implicit TLP lost, -18%). R6: all GEMMs 128-wide n (R4 evidence:
// NT=128 was ~cost-neutral even carrying the dbuf penalty -> positive alone;
// halves A-restaging blocks, doubles MFMA per barrier-stall).
// ---------------------------------------------------------------------------
__device__ __forceinline__ void gll16(const void* g, void* l) {
  __builtin_amdgcn_global_load_lds(
      (const __attribute__((address_space(1))) unsigned*)g,
      (__attribute__((address_space(3))) unsigned*)l, 16, 0, 0);
}

__device__ __forceinline__ bf16x8 ldfrag(const s16* lds, int r, int s) {
  return *(const bf16x8*)(lds + r * 64 + ((s ^ (r & 7)) << 3));
}

template<class Epi>
__device__ __forceinline__ void mcore(
    s16* __restrict__ As, s16* __restrict__ Wl,
    const u16* __restrict__ A, const u16* __restrict__ WT,
    int N, int K, int arow0, int n0, Epi epi)
{
  int tid = threadIdx.x;
  int w = tid >> 6, lane = tid & 63;
  int quad = lane >> 4, l15 = lane & 15;
  int r8 = lane >> 3;                          // row-within-chunk 0..7
  int sl = ((lane & 7) ^ r8) * 8;              // pre-swizzled src slot (elems)
  int wm = (w >> 1) * 64, wn = (w & 1) * 64;

  f32x4 acc[4][4];
#pragma unroll
  for (int i = 0; i < 4; i++)
#pragma unroll
    for (int j = 0; j < 4; j++) acc[i][j] = (f32x4){0.f, 0.f, 0.f, 0.f};

  // Per-lane global source pointers (wave w owns 1KB chunks w*4+i;
  // chunk = 8 rows x 64 elems; lane -> row chunk*8+r8, slot sl).
  const u16* Ag[4];
#pragma unroll
  for (int i = 0; i < 4; i++)
    Ag[i] = A + (size_t)(arow0 + (w * 4 + i) * 8 + r8) * K + sl;
  const u16* Wg[4];
#pragma unroll
  for (int i = 0; i < 4; i++)
    Wg[i] = WT + (size_t)(n0 + (w * 4 + i) * 8 + r8) * K + sl;

  for (int k0 = 0; k0 < K; k0 += 64) {
    __syncthreads();                 // prior iter's ds_reads done (all waves)
#pragma unroll
    for (int i = 0; i < 4; i++)
      gll16(Ag[i] + k0, As + (w * 4 + i) * 512);
#pragma unroll
    for (int i = 0; i < 4; i++)
      gll16(Wg[i] + k0, Wl + (w * 4 + i) * 512);
    __syncthreads();                 // vmcnt(0) drain: DMA data visible
#pragma unroll
    for (int kh = 0; kh < 2; kh++) {
      bf16x8 am[4], bn[4];
#pragma unroll
      for (int i = 0; i < 4; i++)
        am[i] = ldfrag(As, wm + i * 16 + l15, kh * 4 + quad);
#pragma unroll
      for (int j = 0; j < 4; j++)
        bn[j] = ldfrag(Wl, wn + j * 16 + l15, kh * 4 + quad);
#pragma unroll
      for (int i = 0; i < 4; i++)
#pragma unroll
        for (int j = 0; j < 4; j++)
          acc[i][j] = __builtin_amdgcn_mfma_f32_16x16x32_bf16(am[i], bn[j], acc[i][j], 0, 0, 0);
    }
  }

#pragma unroll
  for (int i = 0; i < 4; i++)
#pragma unroll
    for (int j = 0; j < 4; j++)
#pragma unroll
      for (int r = 0; r < 4; r++) {
        int m = wm + i * 16 + quad * 4 + r;
        int n = n0 + wn + j * 16 + l15;
        if (n < N) epi(m, n, acc[i][j][r]);
      }
}

#define MCORE_LDS \
  __shared__ __attribute__((aligned(16))) s16 As[128 * 64]; \
  __shared__ __attribute__((aligned(16))) s16 Ws[128 * 64];

// QKV N=1152. Swizzled 1D grid (9 * mtiles).
__global__ __launch_bounds__(256) void qkv128(
    const bf16* hc, const bf16* Wbuf, bf16* qkvc, int MCa, int mtiles)
{
  MCORE_LDS
  int nt, mblk;
  swz(blockIdx.x, 9, mtiles, nt, mblk);
  int n0 = nt * 128, mloc0 = mblk * 128;
  auto epi = [&](int m, int n, float v) {
    int mat = n / 384;
    int rem = n - mat * 384;
    int hh = rem >> 6, hd = rem & 63;
    qkvc[(size_t)mat * MCa * D_ + (size_t)hh * MCa * HD_
         + (size_t)(mloc0 + m) * HD_ + hd] = f2b(v);
  };
  mcore(As, Ws, (const u16*)hc,
        (const u16*)Wbuf + OFF_QKV, 1152, D_, mloc0, n0, epi);
}

// ffn1: ReLU -> midc. Swizzled 1D grid (12 * mtiles).
__global__ __launch_bounds__(256) void ffn1_128(
    const bf16* hc, const bf16* Wbuf, bf16* midc, int mtiles)
{
  MCORE_LDS
  int nt, mblk;
  swz(blockIdx.x, 12, mtiles, nt, mblk);
  int n0 = nt * 128, m0 = mblk * 128;
  const bf16* bias = (const bf16*)Wbuf + OFF_B1;
  auto epi = [&](int m, int n, float v) {
    float r = v + b2f(bias[n]);
    midc[(size_t)(m0 + m) * (4 * D_) + n] = f2b(fmaxf(r, 0.f));
  };
  mcore(As, Ws, (const u16*)hc,
        (const u16*)Wbuf + OFF_W1T, 4 * D_, D_, m0, n0, epi);
}

// proj: resid+bias -> x. Swizzled 1D grid (3 * mtiles).
__global__ __launch_bounds__(256) void proj_mfma(
    const bf16* A, const bf16* Wbuf, bf16* x, int tok0, int mtiles)
{
  MCORE_LDS
  int nt, mblk;
  swz(blockIdx.x, 3, mtiles, nt, mblk);
  int n0 = nt * 128, m0 = mblk * 128;
  const bf16* bias = (const bf16*)Wbuf + OFF_BPROJ;
  auto epi = [&](int m, int n, float v) {
    size_t o = (size_t)(tok0 + m0 + m) * D_ + n;
    x[o] = f2b(v + b2f(bias[n]) + b2f(x[o]));
  };
  mcore(As, Ws, (const u16*)A,
        (const u16*)Wbuf + OFF_PROJ, D_, D_, m0, n0, epi);
}

// ffn2: resid+bias -> x. Swizzled 1D grid (3 * mtiles). K=1536.
__global__ __launch_bounds__(256) void ffn2_mfma(
    const bf16* midc, const bf16* Wbuf, bf16* x, int tok0, int mtiles)
{
  MCORE_LDS
  int nt, mblk;
  swz(blockIdx.x, 3, mtiles, nt, mblk);
  int n0 = nt * 128, m0 = mblk * 128;
  const bf16* bias = (const bf16*)Wbuf + OFF_B2;
  auto epi = [&](int m, int n, float v) {
    size_t o = (size_t)(tok0 + m0 + m) * D_ + n;
    x[o] = f2b(v + b2f(bias[n]) + b2f(x[o]));
  };
  mcore(As, Ws, (const u16*)midc,
        (const u16*)Wbuf + OFF_W2T, D_, 4 * D_, m0, n0, epi);
}

// head: f32 out rows tok0+m. N=65, single 128-wide n-tile (W rows 65..127
// read past Whead into adjacent mapped workspace; garbage only reaches
// masked columns n>=65).
__global__ __launch_bounds__(256) void head_mfma(
    const bf16* hc, const bf16* Hbuf, float* out, int tok0)
{
  MCORE_LDS
  int m0 = blockIdx.x * 128;
  const bf16* bias = (const bf16*)Hbuf + HOFF_BH;
  auto epi = [&](int m, int n, float v) {
    out[(size_t)(tok0 + m0 + m) * V_ + n] = v + b2f(bias[n]);
  };
  mcore(As, Ws, (const u16*)hc,
        (const u16*)Hbuf + HOFF_WHT, V_, D_, m0, 0, epi);
}

// ---------------------------------------------------------------------------
// MFMA flash attention with online softmax.
// R2: V stored TRANSPOSED+XOR-swizzled in LDS at staging time; PV B-frag is
// one ds_read_b128 (was 64 scalar ds_read_u16/thread/tile). Staging lane map
// r=(tid&7)+8*(tid>>6)+32i, slot=(tid>>3)&7 makes the transpose scalar
// writes bank-conflict-free (slot XOR spreads all 8 bank groups, 2 lanes/bank).
// Vt elem (d, r) at d*64 + (((r>>3)^((d>>3)&7))<<3) + (r&7).
// ---------------------------------------------------------------------------
__global__ __launch_bounds__(256) void attn4_kernel(
    const bf16* __restrict__ Q, const bf16* __restrict__ K,
    const bf16* __restrict__ V, bf16* __restrict__ att, int MCa)
{
  __shared__ s16 Qs[64 * 72];
  __shared__ s16 Ks[64 * 72];
  __shared__ __attribute__((aligned(16))) s16 Vt[64 * 64];
  __shared__ s16 Ps[4][16 * 72];
  const float scale = 0.05103103630798288f;   // 384^-0.5 (full-D scaling!)
  int tid = threadIdx.x;
  int w = tid >> 6, lane = tid & 63;
  int quad = lane >> 4, l15 = lane & 15;
  int bid = blockIdx.x;
  int qt = bid & 3;
  int bh = bid >> 2;
  int b = bh / H_, h = bh - b * H_;
  size_t base = ((size_t)h * MCa + (size_t)b * T_) * HD_;
  int q0 = qt * 64;
  int cq = qt;

  int rstg = (tid & 7) + 8 * (tid >> 6);   // + 32*i in loop (rows 0..63)
  int sstg = (tid >> 3) & 7;               // 16B slot 0..7

#pragma unroll
  for (int i = 0; i < 2; i++) {
    int r = rstg + 32 * i;
    *(bf16x8*)&Qs[r * 72 + sstg * 8] =
        *(const bf16x8*)((const u16*)Q + base + (size_t)(q0 + r) * HD_ + sstg * 8);
  }

  float mrow[4] = {-1e30f, -1e30f, -1e30f, -1e30f};
  float lrow[4] = {0.f, 0.f, 0.f, 0.f};
  f32x4 O[4];
#pragma unroll
  for (int nt = 0; nt < 4; nt++) O[nt] = (f32x4){0.f, 0.f, 0.f, 0.f};

  for (int c = 0; c <= cq; c++) {
    __syncthreads();
#pragma unroll
    for (int i = 0; i < 2; i++) {
      int r = rstg + 32 * i;
      *(bf16x8*)&Ks[r * 72 + sstg * 8] =
          *(const bf16x8*)((const u16*)K + base + (size_t)(c * 64 + r) * HD_ + sstg * 8);
      bf16x8 vv =
          *(const bf16x8*)((const u16*)V + base + (size_t)(c * 64 + r) * HD_ + sstg * 8);
      int rs = r >> 3, rl = r & 7;
      int so = ((rs ^ sstg) << 3) + rl;
#pragma unroll
      for (int k = 0; k < 8; k++)
        Vt[(sstg * 8 + k) * 64 + so] = vv[k];
    }
    __syncthreads();

    f32x4 S[4];
#pragma unroll
    for (int nt = 0; nt < 4; nt++) S[nt] = (f32x4){0.f, 0.f, 0.f, 0.f};
#pragma unroll
    for (int ks = 0; ks < 2; ks++) {
      int kk = ks * 32 + quad * 8;
      bf16x8 a = *(const bf16x8*)&Qs[(w * 16 + l15) * 72 + kk];
#pragma unroll
      for (int nt = 0; nt < 4; nt++) {
        bf16x8 bb8 = *(const bf16x8*)&Ks[(nt * 16 + l15) * 72 + kk];
        S[nt] = __builtin_amdgcn_mfma_f32_16x16x32_bf16(a, bb8, S[nt], 0, 0, 0);
      }
    }

#pragma unroll
    for (int nt = 0; nt < 4; nt++)
#pragma unroll
      for (int r = 0; r < 4; r++) {
        int qrow = q0 + w * 16 + quad * 4 + r;
        int sg = c * 64 + nt * 16 + l15;
        float v = S[nt][r] * scale;
        S[nt][r] = (sg <= qrow) ? v : -1e30f;
      }

    float alpha[4];
#pragma unroll
    for (int r = 0; r < 4; r++) {
      float mc = fmaxf(fmaxf(S[0][r], S[1][r]), fmaxf(S[2][r], S[3][r]));
#pragma unroll
      for (int o = 1; o < 16; o <<= 1) mc = fmaxf(mc, __shfl_xor(mc, o, 64));
      float mn = fmaxf(mrow[r], mc);
      alpha[r] = __expf(mrow[r] - mn);
      mrow[r] = mn;
      float s = 0.f;
#pragma unroll
      for (int nt = 0; nt < 4; nt++) {
        float p = __expf(S[nt][r] - mn);
        S[nt][r] = p;
        s += p;
      }
#pragma unroll
      for (int o = 1; o < 16; o <<= 1) s += __shfl_xor(s, o, 64);
      lrow[r] = lrow[r] * alpha[r] + s;
    }
#pragma unroll
    for (int nt = 0; nt < 4; nt++)
#pragma unroll
      for (int r = 0; r < 4; r++) O[nt][r] *= alpha[r];

#pragma unroll
    for (int nt = 0; nt < 4; nt++)
#pragma unroll
      for (int r = 0; r < 4; r++)
        Ps[w][(quad * 4 + r) * 72 + nt * 16 + l15] = (s16)f2u(S[nt][r]);
    __syncthreads();
#pragma unroll
    for (int ks = 0; ks < 2; ks++) {
      bf16x8 a = *(const bf16x8*)&Ps[w][l15 * 72 + ks * 32 + quad * 8];
#pragma unroll
      for (int nt = 0; nt < 4; nt++) {
        int d = nt * 16 + l15;
        bf16x8 bb8 = *(const bf16x8*)&Vt[d * 64 +
            (((ks * 4 + quad) ^ ((d >> 3) & 7)) << 3)];
        O[nt] = __builtin_amdgcn_mfma_f32_16x16x32_bf16(a, bb8, O[nt], 0, 0, 0);
      }
    }
  }

#pragma unroll
  for (int r = 0; r < 4; r++) {
    float invl = 1.0f / lrow[r];
#pragma unroll
    for (int nt = 0; nt < 4; nt++) {
      int qrow = q0 + w * 16 + quad * 4 + r;
      att[(size_t)(b * T_ + qrow) * D_ + h * HD_ + nt * 16 + l15] =
          f2b(O[nt][r] * invl);
    }
  }
}

// ---------------------------------------------------------------------------
extern "C" void kernel_launch(void* const* d_in, const int* in_sizes, int n_in,
                              void* d_out, int out_size, void* d_ws, size_t ws_size,
                              hipStream_t stream)
{
  float* out = (float*)d_out;
  dim3 blk(256);
  int outg = (out_size + 255) / 256;

  static const int expected[20] = {
      16384, 24960, 98304, 884736, 884736, 884736, 884736, 2304,
      3538944, 9216, 3538944, 2304, 2304, 2304, 2304, 2304, 384, 384,
      24960, 65};
  if (n_in != 20) { const_kernel<<<outg, blk, 0, stream>>>(out, out_size, 5.0f); return; }
  for (int i = 0; i < 20; i++)
    if (in_sizes[i] != expected[i]) {
      const_kernel<<<outg, blk, 0, stream>>>(out, out_size, 10.0f * (i + 1));
      return;
    }
  if (out_size != BT * V_) { const_kernel<<<outg, blk, 0, stream>>>(out, out_size, 7.0f); return; }

  const void* idx   = d_in[0];
  const void* tok   = d_in[1];
  const void* pos   = d_in[2];
  const void* Wq    = d_in[3];
  const void* Wk    = d_in[4];
  const void* Wv    = d_in[5];
  const void* Wproj = d_in[6];
  const void* bproj = d_in[7];
  const void* W1    = d_in[8];
  const void* b1    = d_in[9];
  const void* W2    = d_in[10];
  const void* b2    = d_in[11];
  const void* ln1g  = d_in[12];
  const void* ln1b  = d_in[13];
  const void* ln2g  = d_in[14];
  const void* ln2b  = d_in[15];
  const void* lnfg  = d_in[16];
  const void* lnfb  = d_in[17];
  const void* Whead = d_in[18];
  const void* bhead = d_in[19];

  // Layout: try 6-layer weight buffer (conv_all, one dispatch); fall back
  // to single-layer buffer (per-layer conv) if workspace is small.
  const size_t off_x  = 256;
  const size_t off_wb = off_x + (size_t)BT * D_ * 2;
  int nl = 6;
  size_t off_hb = off_wb + (size_t)nl * WBUF_E * 2;
  size_t fixed  = off_hb + ((size_t)HBUF_E * 2 + 63) / 64 * 64;
  size_t minchunk = (size_t)5 * (BT / 64) * D_ * 2;
  if (ws_size < fixed + minchunk) {
    nl = 1;
    off_hb = off_wb + (size_t)WBUF_E * 2;
    fixed  = off_hb + ((size_t)HBUF_E * 2 + 63) / 64 * 64;
  }
  if (ws_size < fixed) {
    const_kernel<<<outg, blk, 0, stream>>>(out, out_size, 0.0f);
    return;
  }
  size_t region = ws_size - fixed;

  // Chunk region = 5 units of MCc*D bf16 (attn: hc|qkv3|att; ffn: hc|mid4).
  int nc = 0;
  const int candn[7] = {1, 2, 4, 8, 16, 32, 64};
  for (int i = 0; i < 7; i++)
    if ((size_t)5 * (BT / candn[i]) * D_ * 2 <= region) { nc = candn[i]; break; }
  if (!nc) { const_kernel<<<outg, blk, 0, stream>>>(out, out_size, 0.0f); return; }
  const int MCc = BT / nc;
  const int CBc = MCc / T_;     // sequences per chunk
  const int mtiles = MCc / 128;

  char* wsb = (char*)d_ws;
  unsigned* flags = (unsigned*)wsb;
  bf16*   x    = (bf16*)(wsb + off_x);
  bf16*   Wbuf = (bf16*)(wsb + off_wb);   // nl layers
  bf16*   Hbuf = (bf16*)(wsb + off_hb);
  bf16*   hc   = (bf16*)(wsb + fixed);
  bf16*   qkvc = hc + (size_t)MCc * D_;
  bf16*   attc = qkvc + (size_t)3 * MCc * D_;
  bf16*   midc = qkvc;                          // overlays qkv+att

  detect_kernel<<<dim3(20), blk, 0, stream>>>(
      tok, pos, Wq, Wk, Wv, Wproj, bproj, W1, b1, W2, b2,
      ln1g, ln1b, ln2g, ln2b, lnfg, lnfb, Whead, bhead,
      (const int*)idx, flags);
  embed_kernel<<<dim3(BT * D_ / 256), blk, 0, stream>>>(idx, tok, pos, x, flags);
  conv_head<<<dim3((HBUF_E + 255) / 256), blk, 0, stream>>>(
      Whead, bhead, lnfg, lnfb, flags, Hbuf);
  if (nl == 6)
    conv_all<<<dim3((6 * WBUF_E + 255) / 256), blk, 0, stream>>>(
        Wq, Wk, Wv, Wproj, bproj, W1, b1, W2, b2,
        ln1g, ln1b, ln2g, ln2b, flags, Wbuf);

  for (int l = 0; l < L_; l++) {
    const bf16* Wl = Wbuf + (nl == 6 ? (size_t)l * WBUF_E : 0);
    if (nl == 1)
      conv_layer<<<dim3((WBUF_E + 255) / 256), blk, 0, stream>>>(
          Wq, Wk, Wv, Wproj, bproj, W1, b1, W2, b2,
          ln1g, ln1b, ln2g, ln2b, flags, Wbuf, l);
    for (int c = 0; c < nc; c++) {
      int tok0 = c * MCc;
      lnw_kernel<<<dim3(MCc / 4), blk, 0, stream>>>(
          x, (const u16*)Wl + OFF_LN1G, (const u16*)Wl + OFF_LN1B, hc, tok0);
      qkv128<<<dim3(9 * mtiles), blk, 0, stream>>>(hc, Wl, qkvc, MCc, mtiles);
      attn4_kernel<<<dim3(CBc * H_ * 4), blk, 0, stream>>>(
          qkvc, qkvc + (size_t)MCc * D_, qkvc + (size_t)2 * MCc * D_, attc, MCc);
      proj_mfma<<<dim3(3 * mtiles), blk, 0, stream>>>(attc, Wl, x, tok0, mtiles);
    }
    for (int f = 0; f < nc; f++) {
      int tok0 = f * MCc;
      lnw_kernel<<<dim3(MCc / 4), blk, 0, stream>>>(
          x, (const u16*)Wl + OFF_LN2G, (const u16*)Wl + OFF_LN2B, hc, tok0);
      ffn1_128<<<dim3(12 * mtiles), blk, 0, stream>>>(hc, Wl, midc, mtiles);
      ffn2_mfma<<<dim3(3 * mtiles), blk, 0, stream>>>(midc, Wl, x, tok0, mtiles);
    }
  }

  for (int c = 0; c < nc; c++) {
    int tok0 = c * MCc;
    lnw_kernel<<<dim3(MCc / 4), blk, 0, stream>>>(
        x, (const u16*)Hbuf + HOFF_LNFG, (const u16*)Hbuf + HOFF_LNFB, hc, tok0);
    head_mfma<<<dim3(MCc / 128), blk, 0, stream>>>(hc, Hbuf, out, tok0);
  }
}

// Round 8
// 1122.505 us; speedup vs baseline: 1.0720x; 1.0720x over previous
//
#include <hip/hip_runtime.h>
#include <hip/hip_bf16.h>

// Problem constants
#define B_  64
#define T_  256
#define D_  384
#define H_  6
#define HD_ 64
#define L_  6
#define V_  65
#define BT  (B_*T_)     // 16384 tokens

typedef __hip_bfloat16 bf16;
typedef unsigned short u16;
typedef short s16;
typedef __attribute__((ext_vector_type(8))) short bf16x8;   // 8 bf16 = 4 VGPR
typedef __attribute__((ext_vector_type(4))) float f32x4;

// Per-layer weight buffer element offsets (bf16 elems)
#define OFF_QKV   0            // rows n = mat*384+h*64+hd, [n][k] 1152x384
#define OFF_PROJ  442368       // [n][k] 384x384
#define OFF_W1T   589824       // [n][k] 1536x384
#define OFF_W2T   1179648      // [n][k] 384x1536
#define OFF_BPROJ 1769472
#define OFF_B1    1769856
#define OFF_B2    1771392
#define OFF_LN1G  1771776
#define OFF_LN1B  1772160
#define OFF_LN2G  1772544
#define OFF_LN2B  1772928
#define WBUF_E    1773312
// Head buffer
#define HOFF_WHT  0            // [n][k] 65x384
#define HOFF_BH   24960
#define HOFF_LNFG 25088
#define HOFF_LNFB 25472
#define HBUF_E    25856

__device__ __forceinline__ float u2f(u16 u) {
  union { unsigned i; float f; } c; c.i = ((unsigned)u) << 16; return c.f;
}
__device__ __forceinline__ bf16 f2b(float x) { return __float2bfloat16(x); }
__device__ __forceinline__ float b2f(bf16 x) { return __bfloat162float(x); }
__device__ __forceinline__ u16 f2u(float x) { bf16 h = f2b(x); return *(u16*)&h; }

__device__ __forceinline__ float pload(const void* p, size_t i, bool f32w) {
  return f32w ? ((const float*)p)[i] : u2f(((const u16*)p)[i]);
}

// XCD-aware swizzle: all n-tiles of one m-tile get block ids congruent mod 8
// -> same XCD -> A-row re-reads hit that XCD's L2. [guide §1: locality only]
__device__ __forceinline__ void swz(int gid, int ntc, int mtiles,
                                    int& nt, int& mblk) {
  if ((mtiles & 7) == 0) {
    int per = ntc << 3;            // 8 m-tiles per group
    int g   = gid / per;
    int rem = gid - g * per;
    nt   = rem >> 3;
    mblk = (g << 3) + (rem & 7);
  } else {
    nt   = gid / mtiles;
    mblk = gid - nt * mtiles;
  }
}

// ---------------------------------------------------------------------------
// Parallel per-tensor dtype detect (R8-proven).
// ---------------------------------------------------------------------------
__global__ __launch_bounds__(256) void detect_kernel(
    const void* p1,  const void* p2,  const void* p3,  const void* p4,
    const void* p5,  const void* p6,  const void* p7,  const void* p8,
    const void* p9,  const void* p10, const void* p11, const void* p12,
    const void* p13, const void* p14, const void* p15, const void* p16,
    const void* p17, const void* p18, const void* p19,
    const int* __restrict__ idx, unsigned* flags)
{
  const void* ps[20] = {nullptr, p1, p2, p3, p4, p5, p6, p7, p8, p9, p10,
                        p11, p12, p13, p14, p15, p16, p17, p18, p19};
  const int esz[20] = {16384, 24960, 98304, 884736, 884736, 884736, 884736,
                       2304, 3538944, 9216, 3538944, 2304, 2304, 2304, 2304,
                       2304, 384, 384, 24960, 65};
  __shared__ int r1[256], r2[256];
  int bid = blockIdx.x, tid = threadIdx.x;
  if (bid == 19) {
    int z = 0;
    for (int m = tid; m < 4096; m += 256) z += (idx[2 * m + 1] == 0) ? 1 : 0;
    r1[tid] = z; __syncthreads();
    for (int s = 128; s > 0; s >>= 1) {
      if (tid < s) r1[tid] += r1[tid + s];
      __syncthreads();
    }
    if (tid == 0) flags[20] = (r1[0] >= 4000) ? 1u : 0u;
    return;
  }
  int j = bid + 1;
  const u16* p = (const u16*)ps[j];
  int ns = esz[j] / 2; if (ns > 1024) ns = 1024;
  int band = 0, nz = 0;
  for (int i = tid; i < ns; i += 256) {
    u16 lo = p[2 * i], hi = p[2 * i + 1];
    int e = (lo >> 7) & 0xFF;
    band += (e >= 100 && e <= 127) ? 1 : 0;
    nz   += (lo | hi) ? 1 : 0;
  }
  r1[tid] = band; r2[tid] = nz; __syncthreads();
  for (int s = 128; s > 0; s >>= 1) {
    if (tid < s) { r1[tid] += r1[tid + s]; r2[tid] += r2[tid + s]; }
    __syncthreads();
  }
  if (tid == 0) flags[j] = (r2[0] > 0 && r1[0] * 2 < ns) ? 1u : 0u;
}

__global__ void const_kernel(float* out, int n, float val) {
  int i = blockIdx.x * 256 + threadIdx.x;
  if (i < n) out[i] = val;
}

// ---------------------------------------------------------------------------
// Weight convert+transpose to bf16 (shared element map).
// ---------------------------------------------------------------------------
__device__ __forceinline__ float conv_val(int e, int l,
    const void* Wq, const void* Wk, const void* Wv, const void* Wproj,
    const void* bproj, const void* W1, const void* b1, const void* W2,
    const void* b2, const void* ln1g, const void* ln1b, const void* ln2g,
    const void* ln2b, const unsigned* __restrict__ flags)
{
  float v;
  if (e < OFF_PROJ) {                       // QKV^T per head
    int math = e / 24576;
    int rem  = e - math * 24576;
    int hd = rem / 384, d = rem - hd * 384;
    int mat = math / 6, hh = math - mat * 6;
    const void* src = (mat == 0 ? Wq : mat == 1 ? Wk : Wv);
    v = pload(src, ((size_t)(l * 6 + hh) * 384 + d) * 64 + hd, flags[3 + mat] != 0);
  } else if (e < OFF_W1T) {                 // Wproj^T
    int e2 = e - OFF_PROJ;
    int n = e2 / 384, d = e2 - n * 384;
    v = pload(Wproj, ((size_t)l * 384 + d) * 384 + n, flags[6] != 0);
  } else if (e < OFF_W2T) {                 // W1^T
    int e2 = e - OFF_W1T;
    int n = e2 / 384, d = e2 - n * 384;
    v = pload(W1, ((size_t)l * 384 + d) * 1536 + n, flags[8] != 0);
  } else if (e < OFF_BPROJ) {               // W2^T
    int e2 = e - OFF_W2T;
    int n = e2 / 1536, k = e2 - n * 1536;
    v = pload(W2, ((size_t)l * 1536 + k) * 384 + n, flags[10] != 0);
  } else {
    int e2 = e - OFF_BPROJ;
    if      (e2 < 384)  v = pload(bproj, (size_t)l * 384 + e2, flags[7] != 0);
    else if (e2 < 1920) v = pload(b1, (size_t)l * 1536 + (e2 - 384), flags[9] != 0);
    else if (e2 < 2304) v = pload(b2, (size_t)l * 384 + (e2 - 1920), flags[11] != 0);
    else if (e2 < 2688) v = pload(ln1g, (size_t)l * 384 + (e2 - 2304), flags[12] != 0);
    else if (e2 < 3072) v = pload(ln1b, (size_t)l * 384 + (e2 - 2688), flags[13] != 0);
    else if (e2 < 3456) v = pload(ln2g, (size_t)l * 384 + (e2 - 3072), flags[14] != 0);
    else                v = pload(ln2b, (size_t)l * 384 + (e2 - 3456), flags[15] != 0);
  }
  return v;
}

__global__ __launch_bounds__(256) void conv_layer(
    const void* Wq, const void* Wk, const void* Wv, const void* Wproj,
    const void* bproj, const void* W1, const void* b1, const void* W2,
    const void* b2, const void* ln1g, const void* ln1b, const void* ln2g,
    const void* ln2b, const unsigned* __restrict__ flags,
    bf16* __restrict__ dst, int l)
{
  int e = blockIdx.x * 256 + threadIdx.x;
  if (e >= WBUF_E) return;
  dst[e] = f2b(conv_val(e, l, Wq, Wk, Wv, Wproj, bproj, W1, b1, W2, b2,
                        ln1g, ln1b, ln2g, ln2b, flags));
}

// All 6 layers in one dispatch (R5: removes 5 launch gaps from the loop).
__global__ __launch_bounds__(256) void conv_all(
    const void* Wq, const void* Wk, const void* Wv, const void* Wproj,
    const void* bproj, const void* W1, const void* b1, const void* W2,
    const void* b2, const void* ln1g, const void* ln1b, const void* ln2g,
    const void* ln2b, const unsigned* __restrict__ flags,
    bf16* __restrict__ dst)
{
  int g = blockIdx.x * 256 + threadIdx.x;
  if (g >= 6 * WBUF_E) return;
  int l = g / WBUF_E;
  int e = g - l * WBUF_E;
  dst[g] = f2b(conv_val(e, l, Wq, Wk, Wv, Wproj, bproj, W1, b1, W2, b2,
                        ln1g, ln1b, ln2g, ln2b, flags));
}

__global__ __launch_bounds__(256) void conv_head(
    const void* Wh, const void* bh, const void* lnfg, const void* lnfb,
    const unsigned* __restrict__ flags, bf16* __restrict__ dst)
{
  int e = blockIdx.x * 256 + threadIdx.x;
  if (e >= HBUF_E) return;
  float v = 0.f;
  if (e < HOFF_BH) {                        // Whead^T [65][384]
    int n = e / 384, d = e - n * 384;
    v = pload(Wh, (size_t)d * 65 + n, flags[18] != 0);
  } else if (e < 25025) {
    v = pload(bh, e - HOFF_BH, flags[19] != 0);
  } else if (e < HOFF_LNFG) {
    v = 0.f;
  } else if (e < HOFF_LNFB) {
    v = pload(lnfg, e - HOFF_LNFG, flags[16] != 0);
  } else {
    v = pload(lnfb, e - HOFF_LNFB, flags[17] != 0);
  }
  dst[e] = f2b(v);
}

// ---------------------------------------------------------------------------
__global__ __launch_bounds__(256) void embed_kernel(
    const void* __restrict__ idx, const void* __restrict__ tok,
    const void* __restrict__ pos, bf16* __restrict__ x,
    const unsigned* __restrict__ flags)
{
  int i   = blockIdx.x * 256 + threadIdx.x;   // < BT*D_
  int tkn = i / D_;
  int d   = i - tkn * D_;
  int t   = tkn & (T_ - 1);
  long long tix;
  if (flags[20]) tix = ((const long long*)idx)[tkn];
  else           tix = ((const int*)idx)[tkn];
  float v = pload(tok, (size_t)tix * D_ + d, flags[1] != 0)
          + pload(pos, (size_t)t * D_ + d, flags[2] != 0);
  x[i] = f2b(v);
}

// ---------------------------------------------------------------------------
// LayerNorm: one wave per token -> hc (chunk-local).
// R8: ushort2-packed loads/stores (4B/lane; G13 — hipcc won't vectorize
// scalar bf16). d = 2*lane + 128*j, j=0..2. Reduction math unchanged.
// ---------------------------------------------------------------------------
__global__ __launch_bounds__(256) void lnw_kernel(
    const bf16* __restrict__ x, const u16* __restrict__ g,
    const u16* __restrict__ b, bf16* __restrict__ hc, int tok0)
{
  int w = threadIdx.x >> 6, lane = threadIdx.x & 63;
  int lm = blockIdx.x * 4 + w;
  const u16* xr = (const u16*)x + (size_t)(tok0 + lm) * D_;
  float v[6]; float s = 0.f;
#pragma unroll
  for (int j = 0; j < 3; j++) {
    unsigned pk = *(const unsigned*)(xr + 2 * lane + 128 * j);
    v[2 * j]     = u2f((u16)(pk & 0xFFFF));
    v[2 * j + 1] = u2f((u16)(pk >> 16));
    s += v[2 * j] + v[2 * j + 1];
  }
#pragma unroll
  for (int o = 1; o < 64; o <<= 1) s += __shfl_xor(s, o, 64);
  float mean = s * (1.0f / D_);
  float sq = 0.f;
#pragma unroll
  for (int j = 0; j < 6; j++) { float d0 = v[j] - mean; sq += d0 * d0; }
#pragma unroll
  for (int o = 1; o < 64; o <<= 1) sq += __shfl_xor(sq, o, 64);
  float inv = 1.0f / sqrtf(sq * (1.0f / D_) + 1e-3f);
  u16* hr = (u16*)hc + (size_t)lm * D_;
#pragma unroll
  for (int j = 0; j < 3; j++) {
    int d = 2 * lane + 128 * j;
    unsigned gg = *(const unsigned*)(g + d);
    unsigned bb = *(const unsigned*)(b + d);
    u16 o0 = f2u((v[2 * j]     - mean) * inv * u2f((u16)(gg & 0xFFFF)) + u2f((u16)(bb & 0xFFFF)));
    u16 o1 = f2u((v[2 * j + 1] - mean) * inv * u2f((u16)(gg >> 16))    + u2f((u16)(bb >> 16)));
    *(unsigned*)(hr + d) = ((unsigned)o1 << 16) | o0;
  }
}

// ---------------------------------------------------------------------------
// mcore: m97-style MFMA GEMM core (R3/R5-proven, single-buffer 2-barrier).
// Tile 128m x NTn x 64k, 256 threads. global_load_lds(16B) DMA staging into
// LINEAR LDS [rows][64] with content-XOR swizzle: LDS[row][slot] holds
// G[row][slot ^ (row&7)] (slot = 16B chunk index 0..7). Source pre-swizzle +
// read-side XOR are the same involution (rule 21); ds_read_b128 frags land
// 2-way = free. 32 KB LDS keeps ~5 blocks/CU (R4 lesson: 64 KB dbuf -> 2
// blocks/CU, -18%). R7 lesson: NT=128 on proj/ffn2/head (grid 384 blocks)
// loses inter-block TLP, -87 us — keep NT=64 there, NT=128 only for
// qkv/ffn1 (grids >= 768 blocks).
// ---------------------------------------------------------------------------
__device__ __forceinline__ void gll16(const void* g, void* l) {
  __builtin_amdgcn_global_load_lds(
      (const __attribute__((address_space(1))) unsigned*)g,
      (__attribute__((address_space(3))) unsigned*)l, 16, 0, 0);
}

__device__ __forceinline__ bf16x8 ldfrag(const s16* lds, int r, int s) {
  return *(const bf16x8*)(lds + r * 64 + ((s ^ (r & 7)) << 3));
}

template<int NT, class Epi>
__device__ __forceinline__ void mcore(
    s16* __restrict__ As, s16* __restrict__ Wl,
    const u16* __restrict__ A, const u16* __restrict__ WT,
    int N, int K, int arow0, int n0, Epi epi)
{
  constexpr int MREP = (NT == 128) ? 4 : 2;   // 16-row m-frags per wave
  constexpr int WPW  = NT / 32;               // W 1KB-chunks per wave
  int tid = threadIdx.x;
  int w = tid >> 6, lane = tid & 63;
  int quad = lane >> 4, l15 = lane & 15;
  int r8 = lane >> 3;                          // row-within-chunk 0..7
  int sl = ((lane & 7) ^ r8) * 8;              // pre-swizzled src slot (elems)
  int wm = (NT == 128) ? ((w >> 1) * 64) : (w * 32);
  int wn = (NT == 128) ? ((w & 1) * 64) : 0;

  f32x4 acc[MREP][4];
#pragma unroll
  for (int i = 0; i < MREP; i++)
#pragma unroll
    for (int j = 0; j < 4; j++) acc[i][j] = (f32x4){0.f, 0.f, 0.f, 0.f};

  // Per-lane global source pointers (chunk cc = wave w owns cc=w*per+i;
  // 1KB chunk = 8 rows x 64 elems; lane -> row cc*8+r8, slot sl).
  const u16* Ag[4];
#pragma unroll
  for (int i = 0; i < 4; i++)
    Ag[i] = A + (size_t)(arow0 + (w * 4 + i) * 8 + r8) * K + sl;
  const u16* Wg[WPW];
#pragma unroll
  for (int i = 0; i < WPW; i++)
    Wg[i] = WT + (size_t)(n0 + (w * WPW + i) * 8 + r8) * K + sl;

  for (int k0 = 0; k0 < K; k0 += 64) {
    __syncthreads();                 // prior iter's ds_reads done (all waves)
#pragma unroll
    for (int i = 0; i < 4; i++)
      gll16(Ag[i] + k0, As + (w * 4 + i) * 512);
#pragma unroll
    for (int i = 0; i < WPW; i++)
      gll16(Wg[i] + k0, Wl + (w * WPW + i) * 512);
    __syncthreads();                 // vmcnt(0) drain: DMA data visible
#pragma unroll
    for (int kh = 0; kh < 2; kh++) {
      bf16x8 am[MREP], bn[4];
#pragma unroll
      for (int i = 0; i < MREP; i++)
        am[i] = ldfrag(As, wm + i * 16 + l15, kh * 4 + quad);
#pragma unroll
      for (int j = 0; j < 4; j++)
        bn[j] = ldfrag(Wl, wn + j * 16 + l15, kh * 4 + quad);
#pragma unroll
      for (int i = 0; i < MREP; i++)
#pragma unroll
        for (int j = 0; j < 4; j++)
          acc[i][j] = __builtin_amdgcn_mfma_f32_16x16x32_bf16(am[i], bn[j], acc[i][j], 0, 0, 0);
    }
  }

#pragma unroll
  for (int i = 0; i < MREP; i++)
#pragma unroll
    for (int j = 0; j < 4; j++)
#pragma unroll
      for (int r = 0; r < 4; r++) {
        int m = wm + i * 16 + quad * 4 + r;
        int n = n0 + wn + j * 16 + l15;
        if (n < N) epi(m, n, acc[i][j][r]);
      }
}

// QKV N=1152. Swizzled 1D grid (9 * mtiles).
__global__ __launch_bounds__(256) void qkv128(
    const bf16* hc, const bf16* Wbuf, bf16* qkvc, int MCa, int mtiles)
{
  __shared__ __attribute__((aligned(16))) s16 As[128 * 64];
  __shared__ __attribute__((aligned(16))) s16 Ws[128 * 64];
  int nt, mblk;
  swz(blockIdx.x, 9, mtiles, nt, mblk);
  int n0 = nt * 128, mloc0 = mblk * 128;
  auto epi = [&](int m, int n, float v) {
    int mat = n / 384;
    int rem = n - mat * 384;
    int hh = rem >> 6, hd = rem & 63;
    qkvc[(size_t)mat * MCa * D_ + (size_t)hh * MCa * HD_
         + (size_t)(mloc0 + m) * HD_ + hd] = f2b(v);
  };
  mcore<128>(As, Ws, (const u16*)hc,
             (const u16*)Wbuf + OFF_QKV, 1152, D_, mloc0, n0, epi);
}

// ffn1: ReLU -> midc. Swizzled 1D grid (12 * mtiles).
__global__ __launch_bounds__(256) void ffn1_128(
    const bf16* hc, const bf16* Wbuf, bf16* midc, int mtiles)
{
  __shared__ __attribute__((aligned(16))) s16 As[128 * 64];
  __shared__ __attribute__((aligned(16))) s16 Ws[128 * 64];
  int nt, mblk;
  swz(blockIdx.x, 12, mtiles, nt, mblk);
  int n0 = nt * 128, m0 = mblk * 128;
  const bf16* bias = (const bf16*)Wbuf + OFF_B1;
  auto epi = [&](int m, int n, float v) {
    float r = v + b2f(bias[n]);
    midc[(size_t)(m0 + m) * (4 * D_) + n] = f2b(fmaxf(r, 0.f));
  };
  mcore<128>(As, Ws, (const u16*)hc,
             (const u16*)Wbuf + OFF_W1T, 4 * D_, D_, m0, n0, epi);
}

// proj: resid+bias -> x. Swizzled 1D grid (6 * mtiles).
__global__ __launch_bounds__(256) void proj_mfma(
    const bf16* A, const bf16* Wbuf, bf16* x, int tok0, int mtiles)
{
  __shared__ __attribute__((aligned(16))) s16 As[128 * 64];
  __shared__ __attribute__((aligned(16))) s16 Ws[64 * 64];
  int nt, mblk;
  swz(blockIdx.x, 6, mtiles, nt, mblk);
  int n0 = nt * 64, m0 = mblk * 128;
  const bf16* bias = (const bf16*)Wbuf + OFF_BPROJ;
  auto epi = [&](int m, int n, float v) {
    size_t o = (size_t)(tok0 + m0 + m) * D_ + n;
    x[o] = f2b(v + b2f(bias[n]) + b2f(x[o]));
  };
  mcore<64>(As, Ws, (const u16*)A,
            (const u16*)Wbuf + OFF_PROJ, D_, D_, m0, n0, epi);
}

// ffn2: resid+bias -> x. Swizzled 1D grid (6 * mtiles). K=1536.
__global__ __launch_bounds__(256) void ffn2_mfma(
    const bf16* midc, const bf16* Wbuf, bf16* x, int tok0, int mtiles)
{
  __shared__ __attribute__((aligned(16))) s16 As[128 * 64];
  __shared__ __attribute__((aligned(16))) s16 Ws[64 * 64];
  int nt, mblk;
  swz(blockIdx.x, 6, mtiles, nt, mblk);
  int n0 = nt * 64, m0 = mblk * 128;
  const bf16* bias = (const bf16*)Wbuf + OFF_B2;
  auto epi = [&](int m, int n, float v) {
    size_t o = (size_t)(tok0 + m0 + m) * D_ + n;
    x[o] = f2b(v + b2f(bias[n]) + b2f(x[o]));
  };
  mcore<64>(As, Ws, (const u16*)midc,
            (const u16*)Wbuf + OFF_W2T, D_, 4 * D_, m0, n0, epi);
}

// head: f32 out rows tok0+m. N=65 (tail tile reads past Hbuf into adjacent
// mapped workspace; garbage only reaches masked columns n>=65).
__global__ __launch_bounds__(256) void head_mfma(
    const bf16* hc, const bf16* Hbuf, float* out, int tok0)
{
  __shared__ __attribute__((aligned(16))) s16 As[128 * 64];
  __shared__ __attribute__((aligned(16))) s16 Ws[64 * 64];
  int n0 = blockIdx.x * 64, m0 = blockIdx.y * 128;
  const bf16* bias = (const bf16*)Hbuf + HOFF_BH;
  auto epi = [&](int m, int n, float v) {
    out[(size_t)(tok0 + m0 + m) * V_ + n] = v + b2f(bias[n]);
  };
  mcore<64>(As, Ws, (const u16*)hc,
            (const u16*)Hbuf + HOFF_WHT, V_, D_, m0, n0, epi);
}

// ---------------------------------------------------------------------------
// MFMA flash attention with online softmax.
// R2: V stored TRANSPOSED+XOR-swizzled in LDS at staging time; PV B-frag is
// one ds_read_b128 (was 64 scalar ds_read_u16/thread/tile). Staging lane map
// r=(tid&7)+8*(tid>>6)+32i, slot=(tid>>3)&7 makes the transpose scalar
// writes bank-conflict-free (slot XOR spreads all 8 bank groups, 2 lanes/bank).
// Vt elem (d, r) at d*64 + (((r>>3)^((d>>3)&7))<<3) + (r&7).
// ---------------------------------------------------------------------------
__global__ __launch_bounds__(256) void attn4_kernel(
    const bf16* __restrict__ Q, const bf16* __restrict__ K,
    const bf16* __restrict__ V, bf16* __restrict__ att, int MCa)
{
  __shared__ s16 Qs[64 * 72];
  __shared__ s16 Ks[64 * 72];
  __shared__ __attribute__((aligned(16))) s16 Vt[64 * 64];
  __shared__ s16 Ps[4][16 * 72];
  const float scale = 0.05103103630798288f;   // 384^-0.5 (full-D scaling!)
  int tid = threadIdx.x;
  int w = tid >> 6, lane = tid & 63;
  int quad = lane >> 4, l15 = lane & 15;
  int bid = blockIdx.x;
  int qt = bid & 3;
  int bh = bid >> 2;
  int b = bh / H_, h = bh - b * H_;
  size_t base = ((size_t)h * MCa + (size_t)b * T_) * HD_;
  int q0 = qt * 64;
  int cq = qt;

  int rstg = (tid & 7) + 8 * (tid >> 6);   // + 32*i in loop (rows 0..63)
  int sstg = (tid >> 3) & 7;               // 16B slot 0..7

#pragma unroll
  for (int i = 0; i < 2; i++) {
    int r = rstg + 32 * i;
    *(bf16x8*)&Qs[r * 72 + sstg * 8] =
        *(const bf16x8*)((const u16*)Q + base + (size_t)(q0 + r) * HD_ + sstg * 8);
  }

  float mrow[4] = {-1e30f, -1e30f, -1e30f, -1e30f};
  float lrow[4] = {0.f, 0.f, 0.f, 0.f};
  f32x4 O[4];
#pragma unroll
  for (int nt = 0; nt < 4; nt++) O[nt] = (f32x4){0.f, 0.f, 0.f, 0.f};

  for (int c = 0; c <= cq; c++) {
    __syncthreads();
#pragma unroll
    for (int i = 0; i < 2; i++) {
      int r = rstg + 32 * i;
      *(bf16x8*)&Ks[r * 72 + sstg * 8] =
          *(const bf16x8*)((const u16*)K + base + (size_t)(c * 64 + r) * HD_ + sstg * 8);
      bf16x8 vv =
          *(const bf16x8*)((const u16*)V + base + (size_t)(c * 64 + r) * HD_ + sstg * 8);
      int rs = r >> 3, rl = r & 7;
      int so = ((rs ^ sstg) << 3) + rl;
#pragma unroll
      for (int k = 0; k < 8; k++)
        Vt[(sstg * 8 + k) * 64 + so] = vv[k];
    }
    __syncthreads();

    f32x4 S[4];
#pragma unroll
    for (int nt = 0; nt < 4; nt++) S[nt] = (f32x4){0.f, 0.f, 0.f, 0.f};
#pragma unroll
    for (int ks = 0; ks < 2; ks++) {
      int kk = ks * 32 + quad * 8;
      bf16x8 a = *(const bf16x8*)&Qs[(w * 16 + l15) * 72 + kk];
#pragma unroll
      for (int nt = 0; nt < 4; nt++) {
        bf16x8 bb8 = *(const bf16x8*)&Ks[(nt * 16 + l15) * 72 + kk];
        S[nt] = __builtin_amdgcn_mfma_f32_16x16x32_bf16(a, bb8, S[nt], 0, 0, 0);
      }
    }

#pragma unroll
    for (int nt = 0; nt < 4; nt++)
#pragma unroll
      for (int r = 0; r < 4; r++) {
        int qrow = q0 + w * 16 + quad * 4 + r;
        int sg = c * 64 + nt * 16 + l15;
        float v = S[nt][r] * scale;
        S[nt][r] = (sg <= qrow) ? v : -1e30f;
      }

    float alpha[4];
#pragma unroll
    for (int r = 0; r < 4; r++) {
      float mc = fmaxf(fmaxf(S[0][r], S[1][r]), fmaxf(S[2][r], S[3][r]));
#pragma unroll
      for (int o = 1; o < 16; o <<= 1) mc = fmaxf(mc, __shfl_xor(mc, o, 64));
      float mn = fmaxf(mrow[r], mc);
      alpha[r] = __expf(mrow[r] - mn);
      mrow[r] = mn;
      float s = 0.f;
#pragma unroll
      for (int nt = 0; nt < 4; nt++) {
        float p = __expf(S[nt][r] - mn);
        S[nt][r] = p;
        s += p;
      }
#pragma unroll
      for (int o = 1; o < 16; o <<= 1) s += __shfl_xor(s, o, 64);
      lrow[r] = lrow[r] * alpha[r] + s;
    }
#pragma unroll
    for (int nt = 0; nt < 4; nt++)
#pragma unroll
      for (int r = 0; r < 4; r++) O[nt][r] *= alpha[r];

#pragma unroll
    for (int nt = 0; nt < 4; nt++)
#pragma unroll
      for (int r = 0; r < 4; r++)
        Ps[w][(quad * 4 + r) * 72 + nt * 16 + l15] = (s16)f2u(S[nt][r]);
    __syncthreads();
#pragma unroll
    for (int ks = 0; ks < 2; ks++) {
      bf16x8 a = *(const bf16x8*)&Ps[w][l15 * 72 + ks * 32 + quad * 8];
#pragma unroll
      for (int nt = 0; nt < 4; nt++) {
        int d = nt * 16 + l15;
        bf16x8 bb8 = *(const bf16x8*)&Vt[d * 64 +
            (((ks * 4 + quad) ^ ((d >> 3) & 7)) << 3)];
        O[nt] = __builtin_amdgcn_mfma_f32_16x16x32_bf16(a, bb8, O[nt], 0, 0, 0);
      }
    }
  }

#pragma unroll
  for (int r = 0; r < 4; r++) {
    float invl = 1.0f / lrow[r];
#pragma unroll
    for (int nt = 0; nt < 4; nt++) {
      int qrow = q0 + w * 16 + quad * 4 + r;
      att[(size_t)(b * T_ + qrow) * D_ + h * HD_ + nt * 16 + l15] =
          f2b(O[nt][r] * invl);
    }
  }
}

// ---------------------------------------------------------------------------
extern "C" void kernel_launch(void* const* d_in, const int* in_sizes, int n_in,
                              void* d_out, int out_size, void* d_ws, size_t ws_size,
                              hipStream_t stream)
{
  float* out = (float*)d_out;
  dim3 blk(256);
  int outg = (out_size + 255) / 256;

  static const int expected[20] = {
      16384, 24960, 98304, 884736, 884736, 884736, 884736, 2304,
      3538944, 9216, 3538944, 2304, 2304, 2304, 2304, 2304, 384, 384,
      24960, 65};
  if (n_in != 20) { const_kernel<<<outg, blk, 0, stream>>>(out, out_size, 5.0f); return; }
  for (int i = 0; i < 20; i++)
    if (in_sizes[i] != expected[i]) {
      const_kernel<<<outg, blk, 0, stream>>>(out, out_size, 10.0f * (i + 1));
      return;
    }
  if (out_size != BT * V_) { const_kernel<<<outg, blk, 0, stream>>>(out, out_size, 7.0f); return; }

  const void* idx   = d_in[0];
  const void* tok   = d_in[1];
  const void* pos   = d_in[2];
  const void* Wq    = d_in[3];
  const void* Wk    = d_in[4];
  const void* Wv    = d_in[5];
  const void* Wproj = d_in[6];
  const void* bproj = d_in[7];
  const void* W1    = d_in[8];
  const void* b1    = d_in[9];
  const void* W2    = d_in[10];
  const void* b2    = d_in[11];
  const void* ln1g  = d_in[12];
  const void* ln1b  = d_in[13];
  const void* ln2g  = d_in[14];
  const void* ln2b  = d_in[15];
  const void* lnfg  = d_in[16];
  const void* lnfb  = d_in[17];
  const void* Whead = d_in[18];
  const void* bhead = d_in[19];

  // Layout: try 6-layer weight buffer (conv_all, one dispatch); fall back
  // to single-layer buffer (per-layer conv) if workspace is small.
  const size_t off_x  = 256;
  const size_t off_wb = off_x + (size_t)BT * D_ * 2;
  int nl = 6;
  size_t off_hb = off_wb + (size_t)nl * WBUF_E * 2;
  size_t fixed  = off_hb + ((size_t)HBUF_E * 2 + 63) / 64 * 64;
  size_t minchunk = (size_t)5 * (BT / 64) * D_ * 2;
  if (ws_size < fixed + minchunk) {
    nl = 1;
    off_hb = off_wb + (size_t)WBUF_E * 2;
    fixed  = off_hb + ((size_t)HBUF_E * 2 + 63) / 64 * 64;
  }
  if (ws_size < fixed) {
    const_kernel<<<outg, blk, 0, stream>>>(out, out_size, 0.0f);
    return;
  }
  size_t region = ws_size - fixed;

  // Chunk region = 5 units of MCc*D bf16 (attn: hc|qkv3|att; ffn: hc|mid4).
  int nc = 0;
  const int candn[7] = {1, 2, 4, 8, 16, 32, 64};
  for (int i = 0; i < 7; i++)
    if ((size_t)5 * (BT / candn[i]) * D_ * 2 <= region) { nc = candn[i]; break; }
  if (!nc) { const_kernel<<<outg, blk, 0, stream>>>(out, out_size, 0.0f); return; }
  const int MCc = BT / nc;
  const int CBc = MCc / T_;     // sequences per chunk
  const int mtiles = MCc / 128;

  char* wsb = (char*)d_ws;
  unsigned* flags = (unsigned*)wsb;
  bf16*   x    = (bf16*)(wsb + off_x);
  bf16*   Wbuf = (bf16*)(wsb + off_wb);   // nl layers
  bf16*   Hbuf = (bf16*)(wsb + off_hb);
  bf16*   hc   = (bf16*)(wsb + fixed);
  bf16*   qkvc = hc + (size_t)MCc * D_;
  bf16*   attc = qkvc + (size_t)3 * MCc * D_;
  bf16*   midc = qkvc;                          // overlays qkv+att

  detect_kernel<<<dim3(20), blk, 0, stream>>>(
      tok, pos, Wq, Wk, Wv, Wproj, bproj, W1, b1, W2, b2,
      ln1g, ln1b, ln2g, ln2b, lnfg, lnfb, Whead, bhead,
      (const int*)idx, flags);
  embed_kernel<<<dim3(BT * D_ / 256), blk, 0, stream>>>(idx, tok, pos, x, flags);
  conv_head<<<dim3((HBUF_E + 255) / 256), blk, 0, stream>>>(
      Whead, bhead, lnfg, lnfb, flags, Hbuf);
  if (nl == 6)
    conv_all<<<dim3((6 * WBUF_E + 255) / 256), blk, 0, stream>>>(
        Wq, Wk, Wv, Wproj, bproj, W1, b1, W2, b2,
        ln1g, ln1b, ln2g, ln2b, flags, Wbuf);

  for (int l = 0; l < L_; l++) {
    const bf16* Wl = Wbuf + (nl == 6 ? (size_t)l * WBUF_E : 0);
    if (nl == 1)
      conv_layer<<<dim3((WBUF_E + 255) / 256), blk, 0, stream>>>(
          Wq, Wk, Wv, Wproj, bproj, W1, b1, W2, b2,
          ln1g, ln1b, ln2g, ln2b, flags, Wbuf, l);
    for (int c = 0; c < nc; c++) {
      int tok0 = c * MCc;
      lnw_kernel<<<dim3(MCc / 4), blk, 0, stream>>>(
          x, (const u16*)Wl + OFF_LN1G, (const u16*)Wl + OFF_LN1B, hc, tok0);
      qkv128<<<dim3(9 * mtiles), blk, 0, stream>>>(hc, Wl, qkvc, MCc, mtiles);
      attn4_kernel<<<dim3(CBc * H_ * 4), blk, 0, stream>>>(
          qkvc, qkvc + (size_t)MCc * D_, qkvc + (size_t)2 * MCc * D_, attc, MCc);
      proj_mfma<<<dim3(6 * mtiles), blk, 0, stream>>>(attc, Wl, x, tok0, mtiles);
    }
    for (int f = 0; f < nc; f++) {
      int tok0 = f * MCc;
      lnw_kernel<<<dim3(MCc / 4), blk, 0, stream>>>(
          x, (const u16*)Wl + OFF_LN2G, (const u16*)Wl + OFF_LN2B, hc, tok0);
      ffn1_128<<<dim3(12 * mtiles), blk, 0, stream>>>(hc, Wl, midc, mtiles);
      ffn2_mfma<<<dim3(6 * mtiles), blk, 0, stream>>>(midc, Wl, x, tok0, mtiles);
    }
  }

  for (int c = 0; c < nc; c++) {
    int tok0 = c * MCc;
    lnw_kernel<<<dim3(MCc / 4), blk, 0, stream>>>(
        x, (const u16*)Hbuf + HOFF_LNFG, (const u16*)Hbuf + HOFF_LNFB, hc, tok0);
    head_mfma<<<dim3(2, MCc / 128), blk, 0, stream>>>(hc, Hbuf, out, tok0);
  }
}

// Round 9
// 1039.006 us; speedup vs baseline: 1.1581x; 1.0804x over previous
//
#include <hip/hip_runtime.h>
#include <hip/hip_bf16.h>

// Problem constants
#define B_  64
#define T_  256
#define D_  384
#define H_  6
#define HD_ 64
#define L_  6
#define V_  65
#define BT  (B_*T_)     // 16384 tokens

typedef __hip_bfloat16 bf16;
typedef unsigned short u16;
typedef short s16;
typedef __attribute__((ext_vector_type(8))) short bf16x8;   // 8 bf16 = 4 VGPR
typedef __attribute__((ext_vector_type(4))) float f32x4;

// Per-layer weight buffer element offsets (bf16 elems)
#define OFF_QKV   0            // rows n = mat*384+h*64+hd, [n][k] 1152x384
#define OFF_PROJ  442368       // [n][k] 384x384
#define OFF_W1T   589824       // [n][k] 1536x384
#define OFF_W2T   1179648      // [n][k] 384x1536
#define OFF_BPROJ 1769472
#define OFF_B1    1769856
#define OFF_B2    1771392
#define OFF_LN1G  1771776
#define OFF_LN1B  1772160
#define OFF_LN2G  1772544
#define OFF_LN2B  1772928
#define WBUF_E    1773312
// Head buffer
#define HOFF_WHT  0            // [n][k] 65x384
#define HOFF_BH   24960
#define HOFF_LNFG 25088
#define HOFF_LNFB 25472
#define HBUF_E    25856

__device__ __forceinline__ float u2f(u16 u) {
  union { unsigned i; float f; } c; c.i = ((unsigned)u) << 16; return c.f;
}
__device__ __forceinline__ bf16 f2b(float x) { return __float2bfloat16(x); }
__device__ __forceinline__ float b2f(bf16 x) { return __bfloat162float(x); }
__device__ __forceinline__ u16 f2u(float x) { bf16 h = f2b(x); return *(u16*)&h; }

__device__ __forceinline__ float pload(const void* p, size_t i, bool f32w) {
  return f32w ? ((const float*)p)[i] : u2f(((const u16*)p)[i]);
}

// XCD-aware swizzle: all n-tiles of one m-tile get block ids congruent mod 8
// -> same XCD -> A-row re-reads hit that XCD's L2. [guide §1: locality only]
__device__ __forceinline__ void swz(int gid, int ntc, int mtiles,
                                    int& nt, int& mblk) {
  if ((mtiles & 7) == 0) {
    int per = ntc << 3;            // 8 m-tiles per group
    int g   = gid / per;
    int rem = gid - g * per;
    nt   = rem >> 3;
    mblk = (g << 3) + (rem & 7);
  } else {
    nt   = gid / mtiles;
    mblk = gid - nt * mtiles;
  }
}

// ---------------------------------------------------------------------------
// Parallel per-tensor dtype detect (R8-proven).
// ---------------------------------------------------------------------------
__global__ __launch_bounds__(256) void detect_kernel(
    const void* p1,  const void* p2,  const void* p3,  const void* p4,
    const void* p5,  const void* p6,  const void* p7,  const void* p8,
    const void* p9,  const void* p10, const void* p11, const void* p12,
    const void* p13, const void* p14, const void* p15, const void* p16,
    const void* p17, const void* p18, const void* p19,
    const int* __restrict__ idx, unsigned* flags)
{
  const void* ps[20] = {nullptr, p1, p2, p3, p4, p5, p6, p7, p8, p9, p10,
                        p11, p12, p13, p14, p15, p16, p17, p18, p19};
  const int esz[20] = {16384, 24960, 98304, 884736, 884736, 884736, 884736,
                       2304, 3538944, 9216, 3538944, 2304, 2304, 2304, 2304,
                       2304, 384, 384, 24960, 65};
  __shared__ int r1[256], r2[256];
  int bid = blockIdx.x, tid = threadIdx.x;
  if (bid == 19) {
    int z = 0;
    for (int m = tid; m < 4096; m += 256) z += (idx[2 * m + 1] == 0) ? 1 : 0;
    r1[tid] = z; __syncthreads();
    for (int s = 128; s > 0; s >>= 1) {
      if (tid < s) r1[tid] += r1[tid + s];
      __syncthreads();
    }
    if (tid == 0) flags[20] = (r1[0] >= 4000) ? 1u : 0u;
    return;
  }
  int j = bid + 1;
  const u16* p = (const u16*)ps[j];
  int ns = esz[j] / 2; if (ns > 1024) ns = 1024;
  int band = 0, nz = 0;
  for (int i = tid; i < ns; i += 256) {
    u16 lo = p[2 * i], hi = p[2 * i + 1];
    int e = (lo >> 7) & 0xFF;
    band += (e >= 100 && e <= 127) ? 1 : 0;
    nz   += (lo | hi) ? 1 : 0;
  }
  r1[tid] = band; r2[tid] = nz; __syncthreads();
  for (int s = 128; s > 0; s >>= 1) {
    if (tid < s) { r1[tid] += r1[tid + s]; r2[tid] += r2[tid + s]; }
    __syncthreads();
  }
  if (tid == 0) flags[j] = (r2[0] > 0 && r1[0] * 2 < ns) ? 1u : 0u;
}

__global__ void const_kernel(float* out, int n, float val) {
  int i = blockIdx.x * 256 + threadIdx.x;
  if (i < n) out[i] = val;
}

// ---------------------------------------------------------------------------
// Weight convert+transpose to bf16 (shared element map).
// ---------------------------------------------------------------------------
__device__ __forceinline__ float conv_val(int e, int l,
    const void* Wq, const void* Wk, const void* Wv, const void* Wproj,
    const void* bproj, const void* W1, const void* b1, const void* W2,
    const void* b2, const void* ln1g, const void* ln1b, const void* ln2g,
    const void* ln2b, const unsigned* __restrict__ flags)
{
  float v;
  if (e < OFF_PROJ) {                       // QKV^T per head
    int math = e / 24576;
    int rem  = e - math * 24576;
    int hd = rem / 384, d = rem - hd * 384;
    int mat = math / 6, hh = math - mat * 6;
    const void* src = (mat == 0 ? Wq : mat == 1 ? Wk : Wv);
    v = pload(src, ((size_t)(l * 6 + hh) * 384 + d) * 64 + hd, flags[3 + mat] != 0);
  } else if (e < OFF_W1T) {                 // Wproj^T
    int e2 = e - OFF_PROJ;
    int n = e2 / 384, d = e2 - n * 384;
    v = pload(Wproj, ((size_t)l * 384 + d) * 384 + n, flags[6] != 0);
  } else if (e < OFF_W2T) {                 // W1^T
    int e2 = e - OFF_W1T;
    int n = e2 / 384, d = e2 - n * 384;
    v = pload(W1, ((size_t)l * 384 + d) * 1536 + n, flags[8] != 0);
  } else if (e < OFF_BPROJ) {               // W2^T
    int e2 = e - OFF_W2T;
    int n = e2 / 1536, k = e2 - n * 1536;
    v = pload(W2, ((size_t)l * 1536 + k) * 384 + n, flags[10] != 0);
  } else {
    int e2 = e - OFF_BPROJ;
    if      (e2 < 384)  v = pload(bproj, (size_t)l * 384 + e2, flags[7] != 0);
    else if (e2 < 1920) v = pload(b1, (size_t)l * 1536 + (e2 - 384), flags[9] != 0);
    else if (e2 < 2304) v = pload(b2, (size_t)l * 384 + (e2 - 1920), flags[11] != 0);
    else if (e2 < 2688) v = pload(ln1g, (size_t)l * 384 + (e2 - 2304), flags[12] != 0);
    else if (e2 < 3072) v = pload(ln1b, (size_t)l * 384 + (e2 - 2688), flags[13] != 0);
    else if (e2 < 3456) v = pload(ln2g, (size_t)l * 384 + (e2 - 3072), flags[14] != 0);
    else                v = pload(ln2b, (size_t)l * 384 + (e2 - 3456), flags[15] != 0);
  }
  return v;
}

__global__ __launch_bounds__(256) void conv_layer(
    const void* Wq, const void* Wk, const void* Wv, const void* Wproj,
    const void* bproj, const void* W1, const void* b1, const void* W2,
    const void* b2, const void* ln1g, const void* ln1b, const void* ln2g,
    const void* ln2b, const unsigned* __restrict__ flags,
    bf16* __restrict__ dst, int l)
{
  int e = blockIdx.x * 256 + threadIdx.x;
  if (e >= WBUF_E) return;
  dst[e] = f2b(conv_val(e, l, Wq, Wk, Wv, Wproj, bproj, W1, b1, W2, b2,
                        ln1g, ln1b, ln2g, ln2b, flags));
}

// ---------------------------------------------------------------------------
// convT (R9): 64x64 tiled transpose for all weight-matrix regions, 6 layers.
// Coalesced reads (lane = src inner dim) + coalesced bf16 writes (lane = dst
// inner dim) via LDS float[64][65] (pad -> conflict-free both phases).
// Replaces conv_all's 3.3x strided over-fetch (138 MB -> ~43 MB).
// 432 tiles/layer: 108 QKV + 36 proj + 144 W1 + 144 W2.
// ---------------------------------------------------------------------------
__global__ __launch_bounds__(256) void convT(
    const void* Wq, const void* Wk, const void* Wv, const void* Wproj,
    const void* W1, const void* W2,
    const unsigned* __restrict__ flags, bf16* __restrict__ dst)
{
  __shared__ float lds[64][65];
  int g = blockIdx.x;
  int l = g / 432, t = g - l * 432;
  const void* sp; bool f32w;
  size_t s_base; int s_rstride;
  size_t d_base; int d_rstride;
  if (t < 108) {                       // QKV: src [d=384][hd=64] -> dst [hd][d]
    int mh = t / 6, dt = t - mh * 6;   // mh = mat*6+hh (0..17), dt: d-tile
    int mat = mh / 6;
    sp = (mat == 0 ? Wq : mat == 1 ? Wk : Wv);
    f32w = flags[3 + mat] != 0;
    s_base = ((size_t)l * 6 * 384 + (size_t)(mh - mat * 6) * 384 + dt * 64) * 64;
    s_rstride = 64;
    d_base = (size_t)OFF_QKV + (size_t)mh * 24576 + dt * 64;
    d_rstride = 384;
  } else if (t < 144) {                // Wproj: src [d=384][n=384] -> dst [n][d]
    int u = t - 108; int nt = u / 6, dt = u - nt * 6;
    sp = Wproj; f32w = flags[6] != 0;
    s_base = ((size_t)l * 384 + dt * 64) * 384 + nt * 64;
    s_rstride = 384;
    d_base = (size_t)OFF_PROJ + (size_t)nt * 64 * 384 + dt * 64;
    d_rstride = 384;
  } else if (t < 288) {                // W1: src [d=384][n=1536] -> dst [n][d]
    int u = t - 144; int nt = u / 6, dt = u - nt * 6;   // nt 0..23
    sp = W1; f32w = flags[8] != 0;
    s_base = ((size_t)l * 384 + dt * 64) * 1536 + nt * 64;
    s_rstride = 1536;
    d_base = (size_t)OFF_W1T + (size_t)nt * 64 * 384 + dt * 64;
    d_rstride = 384;
  } else {                             // W2: src [k=1536][n=384] -> dst [n][k]
    int u = t - 288; int kt = u / 6, nt = u - kt * 6;   // kt 0..23
    sp = W2; f32w = flags[10] != 0;
    s_base = ((size_t)l * 1536 + kt * 64) * 384 + nt * 64;
    s_rstride = 384;
    d_base = (size_t)OFF_W2T + (size_t)nt * 64 * 1536 + kt * 64;
    d_rstride = 1536;
  }
  int tid = threadIdx.x;
  int rq = tid >> 6, c = tid & 63;     // c: src inner col (lane-contiguous)
#pragma unroll
  for (int p = 0; p < 16; p++) {
    int r = p * 4 + rq;
    lds[c][r] = pload(sp, s_base + (size_t)r * s_rstride + c, f32w);
  }
  __syncthreads();
  bf16* dp = dst + (size_t)l * WBUF_E + d_base;
#pragma unroll
  for (int p = 0; p < 16; p++) {
    int cc = p * 4 + rq;               // dst row = src col; lane c = dst inner
    dp[(size_t)cc * d_rstride + c] = f2b(lds[cc][c]);
  }
}

// Small tail: biases + LN params for all 6 layers (region [OFF_BPROJ, WBUF_E)).
__global__ __launch_bounds__(256) void convsmall(
    const void* Wq, const void* Wk, const void* Wv, const void* Wproj,
    const void* bproj, const void* W1, const void* b1, const void* W2,
    const void* b2, const void* ln1g, const void* ln1b, const void* ln2g,
    const void* ln2b, const unsigned* __restrict__ flags,
    bf16* __restrict__ dst)
{
  int g = blockIdx.x * 256 + threadIdx.x;
  if (g >= 6 * (WBUF_E - OFF_BPROJ)) return;
  int l = g / (WBUF_E - OFF_BPROJ);
  int e = OFF_BPROJ + (g - l * (WBUF_E - OFF_BPROJ));
  dst[(size_t)l * WBUF_E + e] =
      f2b(conv_val(e, l, Wq, Wk, Wv, Wproj, bproj, W1, b1, W2, b2,
                   ln1g, ln1b, ln2g, ln2b, flags));
}

__global__ __launch_bounds__(256) void conv_head(
    const void* Wh, const void* bh, const void* lnfg, const void* lnfb,
    const unsigned* __restrict__ flags, bf16* __restrict__ dst)
{
  int e = blockIdx.x * 256 + threadIdx.x;
  if (e >= HBUF_E) return;
  float v = 0.f;
  if (e < HOFF_BH) {                        // Whead^T [65][384]
    int n = e / 384, d = e - n * 384;
    v = pload(Wh, (size_t)d * 65 + n, flags[18] != 0);
  } else if (e < 25025) {
    v = pload(bh, e - HOFF_BH, flags[19] != 0);
  } else if (e < HOFF_LNFG) {
    v = 0.f;
  } else if (e < HOFF_LNFB) {
    v = pload(lnfg, e - HOFF_LNFG, flags[16] != 0);
  } else {
    v = pload(lnfb, e - HOFF_LNFB, flags[17] != 0);
  }
  dst[e] = f2b(v);
}

// ---------------------------------------------------------------------------
__global__ __launch_bounds__(256) void embed_kernel(
    const void* __restrict__ idx, const void* __restrict__ tok,
    const void* __restrict__ pos, bf16* __restrict__ x,
    const unsigned* __restrict__ flags)
{
  int i   = blockIdx.x * 256 + threadIdx.x;   // < BT*D_
  int tkn = i / D_;
  int d   = i - tkn * D_;
  int t   = tkn & (T_ - 1);
  long long tix;
  if (flags[20]) tix = ((const long long*)idx)[tkn];
  else           tix = ((const int*)idx)[tkn];
  float v = pload(tok, (size_t)tix * D_ + d, flags[1] != 0)
          + pload(pos, (size_t)t * D_ + d, flags[2] != 0);
  x[i] = f2b(v);
}

// ---------------------------------------------------------------------------
// LayerNorm: one wave per token -> hc (chunk-local).
// R8: ushort2-packed loads/stores (4B/lane). Reduction math unchanged.
// ---------------------------------------------------------------------------
__global__ __launch_bounds__(256) void lnw_kernel(
    const bf16* __restrict__ x, const u16* __restrict__ g,
    const u16* __restrict__ b, bf16* __restrict__ hc, int tok0)
{
  int w = threadIdx.x >> 6, lane = threadIdx.x & 63;
  int lm = blockIdx.x * 4 + w;
  const u16* xr = (const u16*)x + (size_t)(tok0 + lm) * D_;
  float v[6]; float s = 0.f;
#pragma unroll
  for (int j = 0; j < 3; j++) {
    unsigned pk = *(const unsigned*)(xr + 2 * lane + 128 * j);
    v[2 * j]     = u2f((u16)(pk & 0xFFFF));
    v[2 * j + 1] = u2f((u16)(pk >> 16));
    s += v[2 * j] + v[2 * j + 1];
  }
#pragma unroll
  for (int o = 1; o < 64; o <<= 1) s += __shfl_xor(s, o, 64);
  float mean = s * (1.0f / D_);
  float sq = 0.f;
#pragma unroll
  for (int j = 0; j < 6; j++) { float d0 = v[j] - mean; sq += d0 * d0; }
#pragma unroll
  for (int o = 1; o < 64; o <<= 1) sq += __shfl_xor(sq, o, 64);
  float inv = 1.0f / sqrtf(sq * (1.0f / D_) + 1e-3f);
  u16* hr = (u16*)hc + (size_t)lm * D_;
#pragma unroll
  for (int j = 0; j < 3; j++) {
    int d = 2 * lane + 128 * j;
    unsigned gg = *(const unsigned*)(g + d);
    unsigned bb = *(const unsigned*)(b + d);
    u16 o0 = f2u((v[2 * j]     - mean) * inv * u2f((u16)(gg & 0xFFFF)) + u2f((u16)(bb & 0xFFFF)));
    u16 o1 = f2u((v[2 * j + 1] - mean) * inv * u2f((u16)(gg >> 16))    + u2f((u16)(bb >> 16)));
    *(unsigned*)(hr + d) = ((unsigned)o1 << 16) | o0;
  }
}

// ---------------------------------------------------------------------------
// mcore: m97-style MFMA GEMM core (R3/R5-proven, single-buffer 2-barrier).
// Tile 128m x NTn x 64k, 256 threads. global_load_lds(16B) DMA staging into
// LINEAR LDS [rows][64] with content-XOR swizzle. 32 KB LDS keeps ~5
// blocks/CU (R4 lesson: 64 KB dbuf -> -18%). R7 lesson: NT=128 only where
// grid >= 768 blocks (qkv/ffn1); NT=64 for proj/ffn2/head.
// ---------------------------------------------------------------------------
__device__ __forceinline__ void gll16(const void* g, void* l) {
  __builtin_amdgcn_global_load_lds(
      (const __attribute__((address_space(1))) unsigned*)g,
      (__attribute__((address_space(3))) unsigned*)l, 16, 0, 0);
}

__device__ __forceinline__ bf16x8 ldfrag(const s16* lds, int r, int s) {
  return *(const bf16x8*)(lds + r * 64 + ((s ^ (r & 7)) << 3));
}

template<int NT, class Epi>
__device__ __forceinline__ void mcore(
    s16* __restrict__ As, s16* __restrict__ Wl,
    const u16* __restrict__ A, const u16* __restrict__ WT,
    int N, int K, int arow0, int n0, Epi epi)
{
  constexpr int MREP = (NT == 128) ? 4 : 2;   // 16-row m-frags per wave
  constexpr int WPW  = NT / 32;               // W 1KB-chunks per wave
  int tid = threadIdx.x;
  int w = tid >> 6, lane = tid & 63;
  int quad = lane >> 4, l15 = lane & 15;
  int r8 = lane >> 3;                          // row-within-chunk 0..7
  int sl = ((lane & 7) ^ r8) * 8;              // pre-swizzled src slot (elems)
  int wm = (NT == 128) ? ((w >> 1) * 64) : (w * 32);
  int wn = (NT == 128) ? ((w & 1) * 64) : 0;

  f32x4 acc[MREP][4];
#pragma unroll
  for (int i = 0; i < MREP; i++)
#pragma unroll
    for (int j = 0; j < 4; j++) acc[i][j] = (f32x4){0.f, 0.f, 0.f, 0.f};

  const u16* Ag[4];
#pragma unroll
  for (int i = 0; i < 4; i++)
    Ag[i] = A + (size_t)(arow0 + (w * 4 + i) * 8 + r8) * K + sl;
  const u16* Wg[WPW];
#pragma unroll
  for (int i = 0; i < WPW; i++)
    Wg[i] = WT + (size_t)(n0 + (w * WPW + i) * 8 + r8) * K + sl;

  for (int k0 = 0; k0 < K; k0 += 64) {
    __syncthreads();                 // prior iter's ds_reads done (all waves)
#pragma unroll
    for (int i = 0; i < 4; i++)
      gll16(Ag[i] + k0, As + (w * 4 + i) * 512);
#pragma unroll
    for (int i = 0; i < WPW; i++)
      gll16(Wg[i] + k0, Wl + (w * WPW + i) * 512);
    __syncthreads();                 // vmcnt(0) drain: DMA data visible
#pragma unroll
    for (int kh = 0; kh < 2; kh++) {
      bf16x8 am[MREP], bn[4];
#pragma unroll
      for (int i = 0; i < MREP; i++)
        am[i] = ldfrag(As, wm + i * 16 + l15, kh * 4 + quad);
#pragma unroll
      for (int j = 0; j < 4; j++)
        bn[j] = ldfrag(Wl, wn + j * 16 + l15, kh * 4 + quad);
#pragma unroll
      for (int i = 0; i < MREP; i++)
#pragma unroll
        for (int j = 0; j < 4; j++)
          acc[i][j] = __builtin_amdgcn_mfma_f32_16x16x32_bf16(am[i], bn[j], acc[i][j], 0, 0, 0);
    }
  }

#pragma unroll
  for (int i = 0; i < MREP; i++)
#pragma unroll
    for (int j = 0; j < 4; j++)
#pragma unroll
      for (int r = 0; r < 4; r++) {
        int m = wm + i * 16 + quad * 4 + r;
        int n = n0 + wn + j * 16 + l15;
        if (n < N) epi(m, n, acc[i][j][r]);
      }
}

// QKV N=1152. Swizzled 1D grid (9 * mtiles).
__global__ __launch_bounds__(256) void qkv128(
    const bf16* hc, const bf16* Wbuf, bf16* qkvc, int MCa, int mtiles)
{
  __shared__ __attribute__((aligned(16))) s16 As[128 * 64];
  __shared__ __attribute__((aligned(16))) s16 Ws[128 * 64];
  int nt, mblk;
  swz(blockIdx.x, 9, mtiles, nt, mblk);
  int n0 = nt * 128, mloc0 = mblk * 128;
  auto epi = [&](int m, int n, float v) {
    int mat = n / 384;
    int rem = n - mat * 384;
    int hh = rem >> 6, hd = rem & 63;
    qkvc[(size_t)mat * MCa * D_ + (size_t)hh * MCa * HD_
         + (size_t)(mloc0 + m) * HD_ + hd] = f2b(v);
  };
  mcore<128>(As, Ws, (const u16*)hc,
             (const u16*)Wbuf + OFF_QKV, 1152, D_, mloc0, n0, epi);
}

// ffn1: ReLU -> midc. Swizzled 1D grid (12 * mtiles).
__global__ __launch_bounds__(256) void ffn1_128(
    const bf16* hc, const bf16* Wbuf, bf16* midc, int mtiles)
{
  __shared__ __attribute__((aligned(16))) s16 As[128 * 64];
  __shared__ __attribute__((aligned(16))) s16 Ws[128 * 64];
  int nt, mblk;
  swz(blockIdx.x, 12, mtiles, nt, mblk);
  int n0 = nt * 128, m0 = mblk * 128;
  const bf16* bias = (const bf16*)Wbuf + OFF_B1;
  auto epi = [&](int m, int n, float v) {
    float r = v + b2f(bias[n]);
    midc[(size_t)(m0 + m) * (4 * D_) + n] = f2b(fmaxf(r, 0.f));
  };
  mcore<128>(As, Ws, (const u16*)hc,
             (const u16*)Wbuf + OFF_W1T, 4 * D_, D_, m0, n0, epi);
}

// proj: resid+bias -> x. Swizzled 1D grid (6 * mtiles).
__global__ __launch_bounds__(256) void proj_mfma(
    const bf16* A, const bf16* Wbuf, bf16* x, int tok0, int mtiles)
{
  __shared__ __attribute__((aligned(16))) s16 As[128 * 64];
  __shared__ __attribute__((aligned(16))) s16 Ws[64 * 64];
  int nt, mblk;
  swz(blockIdx.x, 6, mtiles, nt, mblk);
  int n0 = nt * 64, m0 = mblk * 128;
  const bf16* bias = (const bf16*)Wbuf + OFF_BPROJ;
  auto epi = [&](int m, int n, float v) {
    size_t o = (size_t)(tok0 + m0 + m) * D_ + n;
    x[o] = f2b(v + b2f(bias[n]) + b2f(x[o]));
  };
  mcore<64>(As, Ws, (const u16*)A,
            (const u16*)Wbuf + OFF_PROJ, D_, D_, m0, n0, epi);
}

// ffn2: resid+bias -> x. Swizzled 1D grid (6 * mtiles). K=1536.
__global__ __launch_bounds__(256) void ffn2_mfma(
    const bf16* midc, const bf16* Wbuf, bf16* x, int tok0, int mtiles)
{
  __shared__ __attribute__((aligned(16))) s16 As[128 * 64];
  __shared__ __attribute__((aligned(16))) s16 Ws[64 * 64];
  int nt, mblk;
  swz(blockIdx.x, 6, mtiles, nt, mblk);
  int n0 = nt * 64, m0 = mblk * 128;
  const bf16* bias = (const bf16*)Wbuf + OFF_B2;
  auto epi = [&](int m, int n, float v) {
    size_t o = (size_t)(tok0 + m0 + m) * D_ + n;
    x[o] = f2b(v + b2f(bias[n]) + b2f(x[o]));
  };
  mcore<64>(As, Ws, (const u16*)midc,
            (const u16*)Wbuf + OFF_W2T, D_, 4 * D_, m0, n0, epi);
}

// head: f32 out rows tok0+m. N=65 (tail tile reads past Hbuf into adjacent
// mapped workspace; garbage only reaches masked columns n>=65).
__global__ __launch_bounds__(256) void head_mfma(
    const bf16* hc, const bf16* Hbuf, float* out, int tok0)
{
  __shared__ __attribute__((aligned(16))) s16 As[128 * 64];
  __shared__ __attribute__((aligned(16))) s16 Ws[64 * 64];
  int n0 = blockIdx.x * 64, m0 = blockIdx.y * 128;
  const bf16* bias = (const bf16*)Hbuf + HOFF_BH;
  auto epi = [&](int m, int n, float v) {
    out[(size_t)(tok0 + m0 + m) * V_ + n] = v + b2f(bias[n]);
  };
  mcore<64>(As, Ws, (const u16*)hc,
            (const u16*)Hbuf + HOFF_WHT, V_, D_, m0, n0, epi);
}

// ---------------------------------------------------------------------------
// MFMA flash attention with online softmax (R2-proven).
// ---------------------------------------------------------------------------
__global__ __launch_bounds__(256) void attn4_kernel(
    const bf16* __restrict__ Q, const bf16* __restrict__ K,
    const bf16* __restrict__ V, bf16* __restrict__ att, int MCa)
{
  __shared__ s16 Qs[64 * 72];
  __shared__ s16 Ks[64 * 72];
  __shared__ __attribute__((aligned(16))) s16 Vt[64 * 64];
  __shared__ s16 Ps[4][16 * 72];
  const float scale = 0.05103103630798288f;   // 384^-0.5 (full-D scaling!)
  int tid = threadIdx.x;
  int w = tid >> 6, lane = tid & 63;
  int quad = lane >> 4, l15 = lane & 15;
  int bid = blockIdx.x;
  int qt = bid & 3;
  int bh = bid >> 2;
  int b = bh / H_, h = bh - b * H_;
  size_t base = ((size_t)h * MCa + (size_t)b * T_) * HD_;
  int q0 = qt * 64;
  int cq = qt;

  int rstg = (tid & 7) + 8 * (tid >> 6);   // + 32*i in loop (rows 0..63)
  int sstg = (tid >> 3) & 7;               // 16B slot 0..7

#pragma unroll
  for (int i = 0; i < 2; i++) {
    int r = rstg + 32 * i;
    *(bf16x8*)&Qs[r * 72 + sstg * 8] =
        *(const bf16x8*)((const u16*)Q + base + (size_t)(q0 + r) * HD_ + sstg * 8);
  }

  float mrow[4] = {-1e30f, -1e30f, -1e30f, -1e30f};
  float lrow[4] = {0.f, 0.f, 0.f, 0.f};
  f32x4 O[4];
#pragma unroll
  for (int nt = 0; nt < 4; nt++) O[nt] = (f32x4){0.f, 0.f, 0.f, 0.f};

  for (int c = 0; c <= cq; c++) {
    __syncthreads();
#pragma unroll
    for (int i = 0; i < 2; i++) {
      int r = rstg + 32 * i;
      *(bf16x8*)&Ks[r * 72 + sstg * 8] =
          *(const bf16x8*)((const u16*)K + base + (size_t)(c * 64 + r) * HD_ + sstg * 8);
      bf16x8 vv =
          *(const bf16x8*)((const u16*)V + base + (size_t)(c * 64 + r) * HD_ + sstg * 8);
      int rs = r >> 3, rl = r & 7;
      int so = ((rs ^ sstg) << 3) + rl;
#pragma unroll
      for (int k = 0; k < 8; k++)
        Vt[(sstg * 8 + k) * 64 + so] = vv[k];
    }
    __syncthreads();

    f32x4 S[4];
#pragma unroll
    for (int nt = 0; nt < 4; nt++) S[nt] = (f32x4){0.f, 0.f, 0.f, 0.f};
#pragma unroll
    for (int ks = 0; ks < 2; ks++) {
      int kk = ks * 32 + quad * 8;
      bf16x8 a = *(const bf16x8*)&Qs[(w * 16 + l15) * 72 + kk];
#pragma unroll
      for (int nt = 0; nt < 4; nt++) {
        bf16x8 bb8 = *(const bf16x8*)&Ks[(nt * 16 + l15) * 72 + kk];
        S[nt] = __builtin_amdgcn_mfma_f32_16x16x32_bf16(a, bb8, S[nt], 0, 0, 0);
      }
    }

#pragma unroll
    for (int nt = 0; nt < 4; nt++)
#pragma unroll
      for (int r = 0; r < 4; r++) {
        int qrow = q0 + w * 16 + quad * 4 + r;
        int sg = c * 64 + nt * 16 + l15;
        float v = S[nt][r] * scale;
        S[nt][r] = (sg <= qrow) ? v : -1e30f;
      }

    float alpha[4];
#pragma unroll
    for (int r = 0; r < 4; r++) {
      float mc = fmaxf(fmaxf(S[0][r], S[1][r]), fmaxf(S[2][r], S[3][r]));
#pragma unroll
      for (int o = 1; o < 16; o <<= 1) mc = fmaxf(mc, __shfl_xor(mc, o, 64));
      float mn = fmaxf(mrow[r], mc);
      alpha[r] = __expf(mrow[r] - mn);
      mrow[r] = mn;
      float s = 0.f;
#pragma unroll
      for (int nt = 0; nt < 4; nt++) {
        float p = __expf(S[nt][r] - mn);
        S[nt][r] = p;
        s += p;
      }
#pragma unroll
      for (int o = 1; o < 16; o <<= 1) s += __shfl_xor(s, o, 64);
      lrow[r] = lrow[r] * alpha[r] + s;
    }
#pragma unroll
    for (int nt = 0; nt < 4; nt++)
#pragma unroll
      for (int r = 0; r < 4; r++) O[nt][r] *= alpha[r];

#pragma unroll
    for (int nt = 0; nt < 4; nt++)
#pragma unroll
      for (int r = 0; r < 4; r++)
        Ps[w][(quad * 4 + r) * 72 + nt * 16 + l15] = (s16)f2u(S[nt][r]);
    __syncthreads();
#pragma unroll
    for (int ks = 0; ks < 2; ks++) {
      bf16x8 a = *(const bf16x8*)&Ps[w][l15 * 72 + ks * 32 + quad * 8];
#pragma unroll
      for (int nt = 0; nt < 4; nt++) {
        int d = nt * 16 + l15;
        bf16x8 bb8 = *(const bf16x8*)&Vt[d * 64 +
            (((ks * 4 + quad) ^ ((d >> 3) & 7)) << 3)];
        O[nt] = __builtin_amdgcn_mfma_f32_16x16x32_bf16(a, bb8, O[nt], 0, 0, 0);
      }
    }
  }

#pragma unroll
  for (int r = 0; r < 4; r++) {
    float invl = 1.0f / lrow[r];
#pragma unroll
    for (int nt = 0; nt < 4; nt++) {
      int qrow = q0 + w * 16 + quad * 4 + r;
      att[(size_t)(b * T_ + qrow) * D_ + h * HD_ + nt * 16 + l15] =
          f2b(O[nt][r] * invl);
    }
  }
}

// ---------------------------------------------------------------------------
extern "C" void kernel_launch(void* const* d_in, const int* in_sizes, int n_in,
                              void* d_out, int out_size, void* d_ws, size_t ws_size,
                              hipStream_t stream)
{
  float* out = (float*)d_out;
  dim3 blk(256);
  int outg = (out_size + 255) / 256;

  static const int expected[20] = {
      16384, 24960, 98304, 884736, 884736, 884736, 884736, 2304,
      3538944, 9216, 3538944, 2304, 2304, 2304, 2304, 2304, 384, 384,
      24960, 65};
  if (n_in != 20) { const_kernel<<<outg, blk, 0, stream>>>(out, out_size, 5.0f); return; }
  for (int i = 0; i < 20; i++)
    if (in_sizes[i] != expected[i]) {
      const_kernel<<<outg, blk, 0, stream>>>(out, out_size, 10.0f * (i + 1));
      return;
    }
  if (out_size != BT * V_) { const_kernel<<<outg, blk, 0, stream>>>(out, out_size, 7.0f); return; }

  const void* idx   = d_in[0];
  const void* tok   = d_in[1];
  const void* pos   = d_in[2];
  const void* Wq    = d_in[3];
  const void* Wk    = d_in[4];
  const void* Wv    = d_in[5];
  const void* Wproj = d_in[6];
  const void* bproj = d_in[7];
  const void* W1    = d_in[8];
  const void* b1    = d_in[9];
  const void* W2    = d_in[10];
  const void* b2    = d_in[11];
  const void* ln1g  = d_in[12];
  const void* ln1b  = d_in[13];
  const void* ln2g  = d_in[14];
  const void* ln2b  = d_in[15];
  const void* lnfg  = d_in[16];
  const void* lnfb  = d_in[17];
  const void* Whead = d_in[18];
  const void* bhead = d_in[19];

  // Layout: try 6-layer weight buffer (convT+convsmall, two dispatches);
  // fall back to single-layer buffer (per-layer conv) if workspace is small.
  const size_t off_x  = 256;
  const size_t off_wb = off_x + (size_t)BT * D_ * 2;
  int nl = 6;
  size_t off_hb = off_wb + (size_t)nl * WBUF_E * 2;
  size_t fixed  = off_hb + ((size_t)HBUF_E * 2 + 63) / 64 * 64;
  size_t minchunk = (size_t)5 * (BT / 64) * D_ * 2;
  if (ws_size < fixed + minchunk) {
    nl = 1;
    off_hb = off_wb + (size_t)WBUF_E * 2;
    fixed  = off_hb + ((size_t)HBUF_E * 2 + 63) / 64 * 64;
  }
  if (ws_size < fixed) {
    const_kernel<<<outg, blk, 0, stream>>>(out, out_size, 0.0f);
    return;
  }
  size_t region = ws_size - fixed;

  // Chunk region = 5 units of MCc*D bf16 (attn: hc|qkv3|att; ffn: hc|mid4).
  int nc = 0;
  const int candn[7] = {1, 2, 4, 8, 16, 32, 64};
  for (int i = 0; i < 7; i++)
    if ((size_t)5 * (BT / candn[i]) * D_ * 2 <= region) { nc = candn[i]; break; }
  if (!nc) { const_kernel<<<outg, blk, 0, stream>>>(out, out_size, 0.0f); return; }
  const int MCc = BT / nc;
  const int CBc = MCc / T_;     // sequences per chunk
  const int mtiles = MCc / 128;

  char* wsb = (char*)d_ws;
  unsigned* flags = (unsigned*)wsb;
  bf16*   x    = (bf16*)(wsb + off_x);
  bf16*   Wbuf = (bf16*)(wsb + off_wb);   // nl layers
  bf16*   Hbuf = (bf16*)(wsb + off_hb);
  bf16*   hc   = (bf16*)(wsb + fixed);
  bf16*   qkvc = hc + (size_t)MCc * D_;
  bf16*   attc = qkvc + (size_t)3 * MCc * D_;
  bf16*   midc = qkvc;                          // overlays qkv+att

  detect_kernel<<<dim3(20), blk, 0, stream>>>(
      tok, pos, Wq, Wk, Wv, Wproj, bproj, W1, b1, W2, b2,
      ln1g, ln1b, ln2g, ln2b, lnfg, lnfb, Whead, bhead,
      (const int*)idx, flags);
  embed_kernel<<<dim3(BT * D_ / 256), blk, 0, stream>>>(idx, tok, pos, x, flags);
  conv_head<<<dim3((HBUF_E + 255) / 256), blk, 0, stream>>>(
      Whead, bhead, lnfg, lnfb, flags, Hbuf);
  if (nl == 6) {
    convT<<<dim3(6 * 432), blk, 0, stream>>>(
        Wq, Wk, Wv, Wproj, W1, W2, flags, Wbuf);
    convsmall<<<dim3((6 * (WBUF_E - OFF_BPROJ) + 255) / 256), blk, 0, stream>>>(
        Wq, Wk, Wv, Wproj, bproj, W1, b1, W2, b2,
        ln1g, ln1b, ln2g, ln2b, flags, Wbuf);
  }

  for (int l = 0; l < L_; l++) {
    const bf16* Wl = Wbuf + (nl == 6 ? (size_t)l * WBUF_E : 0);
    if (nl == 1)
      conv_layer<<<dim3((WBUF_E + 255) / 256), blk, 0, stream>>>(
          Wq, Wk, Wv, Wproj, bproj, W1, b1, W2, b2,
          ln1g, ln1b, ln2g, ln2b, flags, Wbuf, l);
    for (int c = 0; c < nc; c++) {
      int tok0 = c * MCc;
      lnw_kernel<<<dim3(MCc / 4), blk, 0, stream>>>(
          x, (const u16*)Wl + OFF_LN1G, (const u16*)Wl + OFF_LN1B, hc, tok0);
      qkv128<<<dim3(9 * mtiles), blk, 0, stream>>>(hc, Wl, qkvc, MCc, mtiles);
      attn4_kernel<<<dim3(CBc * H_ * 4), blk, 0, stream>>>(
          qkvc, qkvc + (size_t)MCc * D_, qkvc + (size_t)2 * MCc * D_, attc, MCc);
      proj_mfma<<<dim3(6 * mtiles), blk, 0, stream>>>(attc, Wl, x, tok0, mtiles);
    }
    for (int f = 0; f < nc; f++) {
      int tok0 = f * MCc;
      lnw_kernel<<<dim3(MCc / 4), blk, 0, stream>>>(
          x, (const u16*)Wl + OFF_LN2G, (const u16*)Wl + OFF_LN2B, hc, tok0);
      ffn1_128<<<dim3(12 * mtiles), blk, 0, stream>>>(hc, Wl, midc, mtiles);
      ffn2_mfma<<<dim3(6 * mtiles), blk, 0, stream>>>(midc, Wl, x, tok0, mtiles);
    }
  }

  for (int c = 0; c < nc; c++) {
    int tok0 = c * MCc;
    lnw_kernel<<<dim3(MCc / 4), blk, 0, stream>>>(
        x, (const u16*)Hbuf + HOFF_LNFG, (const u16*)Hbuf + HOFF_LNFB, hc, tok0);
    head_mfma<<<dim3(2, MCc / 128), blk, 0, stream>>>(hc, Hbuf, out, tok0);
  }
}